// Round 6
// baseline (335.621 us; speedup 1.0000x reference)
//
#include <hip/hip_runtime.h>

typedef unsigned short u16;
typedef __bf16 bf16x8 __attribute__((ext_vector_type(8)));
typedef u16 u16x8 __attribute__((ext_vector_type(8)));
typedef u16 u16x4 __attribute__((ext_vector_type(4)));
typedef float f32x4 __attribute__((ext_vector_type(4)));

__device__ __forceinline__ u16 f2bf(float f) {
    union { float f; unsigned int u; } x; x.f = f;
    unsigned int r = x.u + 0x7FFFu + ((x.u >> 16) & 1u);
    return (u16)(r >> 16);
}

__device__ __forceinline__ u16 f2bf_hw(float f) {
    union { __bf16 b; u16 u; } x; x.b = (__bf16)f; return x.u;
}

// async global -> LDS, 16B per lane. LDS dest is wave-uniform base + lane*16.
__device__ __forceinline__ void gload_lds16(const u16* g, u16* l) {
    __builtin_amdgcn_global_load_lds(
        (const __attribute__((address_space(1))) unsigned int*)g,
        (__attribute__((address_space(3))) unsigned int*)l, 16, 0, 0);
}

// ---------------- merged prep: QKV repack + Wo/W1/W2 transpose + rmsnorm ----------------

__device__ __forceinline__ void transT_body(
    const float* __restrict__ in, u16* __restrict__ out, int R, int C,
    int bx, int by, float T[64][65], int tid)
{
    const int r0 = bx * 64, c0 = by * 64;
    const int tr = tid >> 4;
    const int tc = (tid & 15) * 4;
    #pragma unroll
    for (int k = 0; k < 4; k++) {
        f32x4 v = *(const f32x4*)(in + (size_t)(c0 + 16 * k + tr) * R + r0 + tc);
        T[16 * k + tr][tc]     = v[0];
        T[16 * k + tr][tc + 1] = v[1];
        T[16 * k + tr][tc + 2] = v[2];
        T[16 * k + tr][tc + 3] = v[3];
    }
    __syncthreads();
    #pragma unroll
    for (int k = 0; k < 4; k++) {
        const int rl = 16 * k + tr;
        u16x4 o;
        #pragma unroll
        for (int i = 0; i < 4; i++) o[i] = f2bf(T[tc + i][rl]);
        *(u16x4*)(out + (size_t)(r0 + rl) * C + c0 + tc) = o;
    }
}

__global__ __launch_bounds__(256) void prep_k(
    const float* __restrict__ Wq, const float* __restrict__ Wk,
    const float* __restrict__ Wv, const float* __restrict__ Wo,
    const float* __restrict__ W1, const float* __restrict__ W2,
    const float* __restrict__ x, const float* __restrict__ g1,
    u16* __restrict__ bqkvT, u16* __restrict__ woT,
    u16* __restrict__ w1T, u16* __restrict__ w2T, u16* __restrict__ h1)
{
    __shared__ float T[64][65];
    const int id = blockIdx.x;
    const int tid = threadIdx.x;

    if (id < 768) {
        const int bx = id & 15, y = id >> 4;
        const int d0 = bx * 64;
        const int wsel = y >> 4, h = y & 15;
        const float* W = (wsel == 0) ? Wq : (wsel == 1) ? Wk : Wv;
        const float scale = (wsel == 0) ? 0.125f * 1.44269504088896f : 1.0f;
        const int tr = tid >> 4;
        const int tc = (tid & 15) * 4;
        #pragma unroll
        for (int k = 0; k < 4; k++) {
            f32x4 v = *(const f32x4*)(W + (size_t)h * 65536 + (size_t)(d0 + 16 * k + tr) * 64 + tc);
            T[16 * k + tr][tc]     = v[0];
            T[16 * k + tr][tc + 1] = v[1];
            T[16 * k + tr][tc + 2] = v[2];
            T[16 * k + tr][tc + 3] = v[3];
        }
        __syncthreads();
        #pragma unroll
        for (int k = 0; k < 4; k++) {
            const int kk = 16 * k + tr;
            u16x4 o;
            #pragma unroll
            for (int i = 0; i < 4; i++) o[i] = f2bf(T[tc + i][kk] * scale);
            *(u16x4*)(bqkvT + (size_t)(wsel * 1024 + h * 64 + kk) * 1024 + d0 + tc) = o;
        }
    } else if (id < 1024) {
        const int id2 = id - 768;
        transT_body(Wo, woT, 1024, 1024, id2 & 15, id2 >> 4, T, tid);
    } else if (id < 2048) {
        const int id3 = id - 1024;
        transT_body(W1, w1T, 4096, 1024, id3 & 63, id3 >> 6, T, tid);
    } else if (id < 3072) {
        const int id4 = id - 2048;
        transT_body(W2, w2T, 1024, 4096, id4 & 15, id4 >> 4, T, tid);
    } else {
        const int row = id - 3072;
        const float* xr = x + (size_t)row * 1024;
        f32x4 v = *(const f32x4*)(xr + tid * 4);
        float ss = v[0] * v[0] + v[1] * v[1] + v[2] * v[2] + v[3] * v[3];
        #pragma unroll
        for (int off = 32; off > 0; off >>= 1) ss += __shfl_down(ss, off);
        float* red = &T[0][0];
        if ((tid & 63) == 0) red[tid >> 6] = ss;
        __syncthreads();
        float sum = red[0] + red[1] + red[2] + red[3];
        float rinv = rsqrtf(sum * (1.0f / 1024.0f) + 1e-6f);
        f32x4 gv = *(const f32x4*)(g1 + tid * 4);
        u16x4 o;
        #pragma unroll
        for (int i = 0; i < 4; i++) o[i] = f2bf(v[i] * gv[i] * rinv);
        *(u16x4*)(h1 + (size_t)row * 1024 + tid * 4) = o;
    }
}

// V^T: vT[(b*16+h)*64 + d][s] = qkvB[s*2+b][2048 + h*64 + d]
__global__ __launch_bounds__(256) void vtrans_k(const u16* __restrict__ qkv, u16* __restrict__ vT)
{
    __shared__ u16 T[64][72];
    const int bh = blockIdx.x, b = bh >> 4, h = bh & 15;
    const int s0 = blockIdx.y * 64;
    const int tid = threadIdx.x;
    const int r = tid >> 2, c0 = (tid & 3) * 16;
    const u16* src = qkv + ((size_t)((s0 + r) * 2 + b)) * 3072 + 2048 + h * 64 + c0;
    *(u16x8*)&T[r][c0] = *(const u16x8*)src;
    *(u16x8*)&T[r][c0 + 8] = *(const u16x8*)(src + 8);
    __syncthreads();
    u16x8 o0, o1;
    #pragma unroll
    for (int i = 0; i < 8; i++) o0[i] = T[c0 + i][r];
    #pragma unroll
    for (int i = 0; i < 8; i++) o1[i] = T[c0 + 8 + i][r];
    u16* dst = vT + (size_t)(bh * 64 + r) * 2048 + s0 + c0;
    *(u16x8*)dst = o0;
    *(u16x8*)(dst + 8) = o1;
}

// xout = res + p0 + p1 ; hout = rmsnorm(xout)*g   (block = one 1024-wide row)
__global__ __launch_bounds__(256) void addred_norm_k(
    const float* __restrict__ res, const float* __restrict__ p0,
    const float* __restrict__ p1, const float* __restrict__ g,
    float* __restrict__ xout, u16* __restrict__ hout)
{
    const int row = blockIdx.x;
    const int tid = threadIdx.x;
    const size_t base = (size_t)row * 1024 + tid * 4;
    f32x4 a = *(const f32x4*)(res + base);
    f32x4 b = *(const f32x4*)(p0 + base);
    f32x4 c = *(const f32x4*)(p1 + base);
    f32x4 o = a + b + c;
    *(f32x4*)(xout + base) = o;
    float ss = o[0] * o[0] + o[1] * o[1] + o[2] * o[2] + o[3] * o[3];
    #pragma unroll
    for (int off = 32; off > 0; off >>= 1) ss += __shfl_down(ss, off);
    __shared__ float red[4];
    if ((tid & 63) == 0) red[tid >> 6] = ss;
    __syncthreads();
    float sum = red[0] + red[1] + red[2] + red[3];
    float rinv = rsqrtf(sum * (1.0f / 1024.0f) + 1e-6f);
    f32x4 gv = *(const f32x4*)(g + tid * 4);
    u16x4 hv;
    #pragma unroll
    for (int i = 0; i < 4; i++) hv[i] = f2bf(o[i] * gv[i] * rinv);
    *(u16x4*)(hout + base) = hv;
}

// out = a0 + a1 + a2 + a3 (a0 already includes the residual, fused in W2 z==0)
__global__ __launch_bounds__(256) void addredW_k(
    const float* __restrict__ a0, const float* __restrict__ a1,
    const float* __restrict__ a2, const float* __restrict__ a3,
    float* __restrict__ out)
{
    int i = (blockIdx.x * 256 + threadIdx.x) * 4;
    f32x4 v = *(const f32x4*)(a0 + i);
    v = v + *(const f32x4*)(a1 + i);
    v = v + *(const f32x4*)(a2 + i);
    v = v + *(const f32x4*)(a3 + i);
    *(f32x4*)(out + i) = v;
}

// ---------------- GEMM (legacy 128x128, kept for Wo) ----------------
template <int MODE>
__global__ __launch_bounds__(256) void gemm_bt_k(
    const u16* __restrict__ A, const u16* __restrict__ BT,
    u16* __restrict__ outB, float* __restrict__ outF, const float* __restrict__ res,
    int M, int N, int K, int klen)
{
    __shared__ u16 As[2][128 * 64];
    __shared__ u16 Bs[2][128 * 64];
    const int tid = threadIdx.x;
    const int lane = tid & 63, w = tid >> 6;
    const int wm = w >> 1, wn = w & 1;
    const int quad = lane >> 4, l15 = lane & 15;
    const int bid = blockIdx.x + gridDim.x * blockIdx.y;
    const int bj = bid >> 3;
    const int m0 = ((bid & 7) * 4 + (bj & 3)) * 128;
    const int n0 = (bj >> 2) * 128;
    const int kbeg = blockIdx.z * klen;

    f32x4 acc[4][4] = {};

    const int srow = (w << 3) + (lane >> 3);
    const int swz = ((lane & 7) ^ (lane >> 3)) << 3;
    const u16* aA = A + (size_t)(m0 + srow) * K + kbeg + swz;
    const u16* aB = BT + (size_t)(n0 + srow) * K + kbeg + swz;
    const int wo = w * 512;
    const int rsw = (l15 & 7) << 3;

    #pragma unroll
    for (int c = 0; c < 4; c++) {
        gload_lds16(aA + (size_t)(c * 32) * K, &As[0][0] + c * 2048 + wo);
        gload_lds16(aB + (size_t)(c * 32) * K, &Bs[0][0] + c * 2048 + wo);
    }

    int cur = 0;
    for (int k0 = 0; k0 < klen; k0 += 64) {
        __syncthreads();
        if (k0 + 64 < klen) {
            #pragma unroll
            for (int c = 0; c < 4; c++) {
                gload_lds16(aA + (size_t)(c * 32) * K + k0 + 64, &As[cur ^ 1][0] + c * 2048 + wo);
                gload_lds16(aB + (size_t)(c * 32) * K + k0 + 64, &Bs[cur ^ 1][0] + c * 2048 + wo);
            }
        }
        const u16* AB = &As[cur][0];
        const u16* BB = &Bs[cur][0];
        #pragma unroll
        for (int kh = 0; kh < 2; kh++) {
            const int cb = ((kh * 4 + quad) << 3);
            bf16x8 af[4], bfr[4];
            #pragma unroll
            for (int i = 0; i < 4; i++)
                af[i] = *(const bf16x8*)(AB + (wm * 64 + i * 16 + l15) * 64 + (cb ^ rsw));
            #pragma unroll
            for (int j = 0; j < 4; j++)
                bfr[j] = *(const bf16x8*)(BB + (wn * 64 + j * 16 + l15) * 64 + (cb ^ rsw));
            #pragma unroll
            for (int i = 0; i < 4; i++)
                #pragma unroll
                for (int j = 0; j < 4; j++)
                    acc[i][j] = __builtin_amdgcn_mfma_f32_16x16x32_bf16(af[i], bfr[j], acc[i][j], 0, 0, 0);
        }
        cur ^= 1;
    }

    float* outFz = (MODE == 3) ? outF + (size_t)blockIdx.z * M * N : outF;
    #pragma unroll
    for (int i = 0; i < 4; i++) {
        const int row = m0 + wm * 64 + i * 16 + quad * 4;
        #pragma unroll
        for (int j = 0; j < 4; j++) {
            const int col = n0 + wn * 64 + j * 16 + l15;
            #pragma unroll
            for (int r = 0; r < 4; r++) {
                const size_t idx = (size_t)(row + r) * N + col;
                float v = acc[i][j][r];
                if (MODE == 0) {
                    outB[idx] = f2bf_hw(v);
                } else if (MODE == 1) {
                    outF[idx] = res[idx] + v;
                } else if (MODE == 2) {
                    float e = exp2f(v * -1.44269504088896f);
                    outB[idx] = f2bf_hw(v * __builtin_amdgcn_rcpf(1.0f + e));
                } else {
                    outFz[idx] = v;
                }
            }
        }
    }
}

// ---------------- GEMM 256x256 8-phase (R5 schedule + z-aware XCD bands for MODE 3) ----
// MODE 3 (W2 split-K=4, grid=256 linear): each XCD owns 2 m-bands x all n x all z so the
// instantaneous A k-slice (~512KB) stays L2-resident; A streams from L3 once per XCD.
// z==0 blocks fuse the residual add (po = v + res) so the final reduce is 4 streams.
#define MMQ(FH, AS, BS) \
    { _Pragma("unroll") \
      for (int i_ = 0; i_ < 4; i_++) { \
        acc[(FH)*4+i_][0] = __builtin_amdgcn_mfma_f32_16x16x32_bf16(AS[i_], BS[0], acc[(FH)*4+i_][0], 0, 0, 0); \
        acc[(FH)*4+i_][1] = __builtin_amdgcn_mfma_f32_16x16x32_bf16(AS[i_], BS[1], acc[(FH)*4+i_][1], 0, 0, 0); \
        acc[(FH)*4+i_][2] = __builtin_amdgcn_mfma_f32_16x16x32_bf16(AS[i_], BS[2], acc[(FH)*4+i_][2], 0, 0, 0); \
        acc[(FH)*4+i_][3] = __builtin_amdgcn_mfma_f32_16x16x32_bf16(AS[i_], BS[3], acc[(FH)*4+i_][3], 0, 0, 0); \
      } }

#define SBAR   __builtin_amdgcn_s_barrier()
#define FENCE  asm volatile("" ::: "memory")

template <int MODE>
__global__ __launch_bounds__(512, 2) void gemm8p_k(
    const u16* __restrict__ A, const u16* __restrict__ BT,
    u16* __restrict__ outB, float* __restrict__ q0, float* __restrict__ q1,
    float* __restrict__ q2, float* __restrict__ q3, const float* __restrict__ res,
    int N, int K, int klen)
{
    __shared__ u16 sm[65536];          // 128 KiB: [buf][A/B][kh][8192]
    const int tid = threadIdx.x;
    const int lane = tid & 63, w = tid >> 6;
    const int l15 = lane & 15, quad = lane >> 4;
    const int wm = w >> 2, wn = w & 3;

    const int nwg = gridDim.x;
    const int bid = blockIdx.x;
    int m0, n0, kbeg, zz = 0;
    if (MODE == 3) {
        // z-aware XCD bands: xcd = bid&7 owns m-bands {2*xcd, 2*xcd+1}, all n, all z.
        const int slot = bid >> 3;
        m0 = ((bid & 7) * 2 + (slot & 1)) * 256;
        n0 = ((slot >> 1) & 3) * 256;
        zz = slot >> 3;
        kbeg = zz * klen;
    } else {
        const int s = (bid & 7) * (nwg >> 3) + (bid >> 3);   // XCD-contiguous bands
        m0 = (s & 15) * 256;                                 // M = 4096 fixed
        n0 = (s >> 4) * 256;
        kbeg = blockIdx.z * klen;
    }
    const int nT = klen >> 6;

    const int srow = w * 16 + (lane >> 2);
    const int scol = (((lane & 3) ^ ((lane >> 3) & 3)) << 3);  // inverse swizzle on source
    const u16* gA = A + (size_t)(m0 + srow) * K + kbeg + scol;
    const u16* gB = BT + (size_t)(n0 + srow) * K + kbeg + scol;
    const size_t cstep = (size_t)128 * K;

    const int rswz = ((quad ^ ((l15 >> 1) & 3)) << 3);
    const int raoff = (wm * 128 + l15) * 32 + rswz;
    const int rboff = (wn * 64 + l15) * 32 + rswz;

    f32x4 acc[8][4] = {};

    auto stA = [&](int t, int kh) {
        u16* d = sm + (t & 1) * 32768 + kh * 8192 + w * 512;
        const u16* g = gA + (size_t)(t * 64 + kh * 32);
        gload_lds16(g, d);
        gload_lds16(g + cstep, d + 4096);
    };
    auto stB = [&](int t, int kh) {
        u16* d = sm + (t & 1) * 32768 + 16384 + kh * 8192 + w * 512;
        const u16* g = gB + (size_t)(t * 64 + kh * 32);
        gload_lds16(g, d);
        gload_lds16(g + cstep, d + 4096);
    };
    auto rdB = [&](int buf, int kh, bf16x8* b) {
        const u16* p = sm + buf * 32768 + 16384 + kh * 8192 + rboff;
        b[0] = *(const bf16x8*)(p);
        b[1] = *(const bf16x8*)(p + 512);
        b[2] = *(const bf16x8*)(p + 1024);
        b[3] = *(const bf16x8*)(p + 1536);
    };
    auto rdA = [&](int buf, int kh, int fh, bf16x8* a) {
        const u16* p = sm + buf * 32768 + kh * 8192 + fh * 2048 + raoff;
        a[0] = *(const bf16x8*)(p);
        a[1] = *(const bf16x8*)(p + 512);
        a[2] = *(const bf16x8*)(p + 1024);
        a[3] = *(const bf16x8*)(p + 1536);
    };

    // prologue: tile0 (4 halves) + tile1 kh0; drain tile0 (8 oldest loads)
    stA(0, 0); stB(0, 0); stA(0, 1); stB(0, 1);
    if (nT > 1) {
        stA(1, 0); stB(1, 0);
        asm volatile("s_waitcnt vmcnt(4)" ::: "memory");
    } else {
        asm volatile("s_waitcnt vmcnt(0)" ::: "memory");
    }
    SBAR; FENCE;

    for (int t = 0; t < nT; t++) {
        const int buf = t & 1;
        bf16x8 a[4], b[4];
        // ph1: fh0 x kh0
        rdA(buf, 0, 0, a); rdB(buf, 0, b);
        if (t + 1 < nT) stA(t + 1, 1);
        SBAR; FENCE;
        __builtin_amdgcn_s_setprio(1);
        MMQ(0, a, b)
        __builtin_amdgcn_s_setprio(0);
        SBAR; FENCE;
        // ph2: fh1 x kh0 (reuse b)
        rdA(buf, 0, 1, a);
        if (t + 1 < nT) stB(t + 1, 1);
        SBAR; FENCE;
        __builtin_amdgcn_s_setprio(1);
        MMQ(1, a, b)
        __builtin_amdgcn_s_setprio(0);
        SBAR; FENCE;
        // ph3: fh0 x kh1
        rdA(buf, 1, 0, a); rdB(buf, 1, b);
        if (t + 2 < nT) stA(t + 2, 0);
        SBAR; FENCE;
        __builtin_amdgcn_s_setprio(1);
        MMQ(0, a, b)
        __builtin_amdgcn_s_setprio(0);
        SBAR; FENCE;
        // ph4: fh1 x kh1 ; counted vmcnt once per tile
        rdA(buf, 1, 1, a);
        if (t + 2 < nT) {
            stB(t + 2, 0);
            asm volatile("s_waitcnt vmcnt(4)" ::: "memory");
        } else {
            asm volatile("s_waitcnt vmcnt(0)" ::: "memory");
        }
        SBAR; FENCE;
        __builtin_amdgcn_s_setprio(1);
        MMQ(1, a, b)
        __builtin_amdgcn_s_setprio(0);
        SBAR; FENCE;
    }

    float* po = nullptr;
    if (MODE == 3)
        po = (zz == 0) ? q0 : (zz == 1) ? q1 : (zz == 2) ? q2 : q3;
    #pragma unroll
    for (int mf = 0; mf < 8; mf++) {
        const int row = m0 + wm * 128 + mf * 16 + quad * 4;
        #pragma unroll
        for (int nf = 0; nf < 4; nf++) {
            const int col = n0 + wn * 64 + nf * 16 + l15;
            #pragma unroll
            for (int r = 0; r < 4; r++) {
                const size_t idx = (size_t)(row + r) * N + col;
                const float v = acc[mf][nf][r];
                if (MODE == 0) {
                    outB[idx] = f2bf_hw(v);
                } else if (MODE == 2) {
                    float e = exp2f(v * -1.44269504088896f);
                    outB[idx] = f2bf_hw(v * __builtin_amdgcn_rcpf(1.0f + e));
                } else {
                    po[idx] = (zz == 0) ? v + res[idx] : v;
                }
            }
        }
    }
}

// ---------------- flash attention (swapped QK^T, in-register softmax) ----------------
__global__ __launch_bounds__(256, 4) void attn_k(const u16* __restrict__ qkv,
                                                 const u16* __restrict__ vT,
                                                 u16* __restrict__ ctx)
{
    const int bh = blockIdx.x;
    const int qt = 31 - (int)blockIdx.y;
    const int b = bh >> 4, h = bh & 15;
    const int q0 = qt * 64;
    const int tid = threadIdx.x;
    const int lane = tid & 63, w = tid >> 6;
    const int quad = lane >> 4, l15 = lane & 15;

    __shared__ u16 Ks[2][4096];
    __shared__ u16 Vs[2][4096];

    const int q = q0 + 16 * w + l15;
    const u16* qrow = qkv + ((size_t)(q * 2 + b)) * 3072 + h * 64;
    const bf16x8 aq0 = *(const bf16x8*)(qrow + quad * 8);
    const bf16x8 aq1 = *(const bf16x8*)(qrow + 32 + quad * 8);

    bf16x8 ones;
    #pragma unroll
    for (int i = 0; i < 8; i++) ones[i] = (__bf16)1.0f;

    const int kr = (w << 3) + (lane >> 3);
    const int swz = ((lane & 7) ^ (lane >> 3)) << 3;
    const int ldsoff = w * 512;
    const u16* kbase0 = qkv + ((size_t)(kr * 2 + b)) * 3072 + 1024 + h * 64 + swz;
    const u16* kbase1 = kbase0 + (size_t)32 * 2 * 3072;
    const u16* vrow0 = vT + (size_t)(bh * 64 + kr) * 2048 + swz;
    const u16* vrow1 = vrow0 + (size_t)32 * 2048;

    const int sl = (l15 & 3) | ((l15 & 4) << 1) | ((l15 & 8) >> 1);
    const int rswk = (sl & 7) << 3;
    const int rswv = (l15 & 7) << 3;
    const int sq = ((quad & 1) << 1) | (quad >> 1);
    const int qloc = 16 * w + l15;

    f32x4 o[4] = {};
    f32x4 accl = {};

    gload_lds16(kbase0, &Ks[0][0] + ldsoff);
    gload_lds16(kbase1, &Ks[0][0] + 2048 + ldsoff);
    gload_lds16(vrow0, &Vs[0][0] + ldsoff);
    gload_lds16(vrow1, &Vs[0][0] + 2048 + ldsoff);

    int cur = 0;
    for (int t0 = 0; t0 <= q0; t0 += 64) {
        __syncthreads();
        if (t0 + 64 <= q0) {
            const size_t go = (size_t)(t0 + 64) * 2 * 3072;
            u16* KB = &Ks[cur ^ 1][0];
            u16* VB = &Vs[cur ^ 1][0];
            gload_lds16(kbase0 + go, KB + ldsoff);
            gload_lds16(kbase1 + go, KB + 2048 + ldsoff);
            gload_lds16(vrow0 + (t0 + 64), VB + ldsoff);
            gload_lds16(vrow1 + (t0 + 64), VB + 2048 + ldsoff);
        }
        const u16* KB = &Ks[cur][0];
        const u16* VB = &Vs[cur][0];

        f32x4 s[4];
        __builtin_amdgcn_s_setprio(1);
        #pragma unroll
        for (int tg = 0; tg < 4; tg++) {
            const u16* kb = KB + (16 * tg + sl) * 64;
            bf16x8 ak0 = *(const bf16x8*)(kb + ((quad << 3) ^ rswk));
            bf16x8 ak1 = *(const bf16x8*)(kb + (((quad + 4) << 3) ^ rswk));
            f32x4 c = {};
            c = __builtin_amdgcn_mfma_f32_16x16x32_bf16(ak0, aq0, c, 0, 0, 0);
            c = __builtin_amdgcn_mfma_f32_16x16x32_bf16(ak1, aq1, c, 0, 0, 0);
            s[tg] = c;
        }
        __builtin_amdgcn_s_setprio(0);

        if (t0 == q0) {
            #pragma unroll
            for (int tg = 0; tg < 4; tg++)
                #pragma unroll
                for (int r = 0; r < 4; r++)
                    if ((16 * tg + 4 * sq + r) > qloc) s[tg][r] = -1e30f;
        }

        unsigned dd[4][2];
        #pragma unroll
        for (int tg = 0; tg < 4; tg++) {
            float e0 = exp2f(s[tg][0]), e1 = exp2f(s[tg][1]);
            float e2 = exp2f(s[tg][2]), e3 = exp2f(s[tg][3]);
            asm("v_cvt_pk_bf16_f32 %0, %1, %2" : "=v"(dd[tg][0]) : "v"(e0), "v"(e1));
            asm("v_cvt_pk_bf16_f32 %0, %1, %2" : "=v"(dd[tg][1]) : "v"(e2), "v"(e3));
        }
        unsigned x0 = dd[0][0], y0 = dd[1][0];
        asm volatile("v_permlane32_swap_b32 %0, %1" : "+v"(x0), "+v"(y0));
        unsigned x1 = dd[0][1], y1 = dd[1][1];
        asm volatile("v_permlane32_swap_b32 %0, %1" : "+v"(x1), "+v"(y1));
        unsigned x2 = dd[2][0], y2 = dd[3][0];
        asm volatile("v_permlane32_swap_b32 %0, %1" : "+v"(x2), "+v"(y2));
        unsigned x3 = dd[2][1], y3 = dd[3][1];
        asm volatile("v_permlane32_swap_b32 %0, %1" : "+v"(x3), "+v"(y3));

        union { unsigned u[4]; bf16x8 v; } pu0, pu1;
        pu0.u[0] = x0; pu0.u[1] = x1; pu0.u[2] = y0; pu0.u[3] = y1;
        pu1.u[0] = x2; pu1.u[1] = x3; pu1.u[2] = y2; pu1.u[3] = y3;
        const bf16x8 pf0 = pu0.v, pf1 = pu1.v;

        __builtin_amdgcn_s_setprio(1);
        accl = __builtin_amdgcn_mfma_f32_16x16x32_bf16(ones, pf0, accl, 0, 0, 0);
        accl = __builtin_amdgcn_mfma_f32_16x16x32_bf16(ones, pf1, accl, 0, 0, 0);
        #pragma unroll
        for (int i = 0; i < 4; i++) {
            const u16* vb = VB + (i * 16 + l15) * 64;
            bf16x8 av0 = *(const bf16x8*)(vb + ((quad << 3) ^ rswv));
            bf16x8 av1 = *(const bf16x8*)(vb + (((quad + 4) << 3) ^ rswv));
            o[i] = __builtin_amdgcn_mfma_f32_16x16x32_bf16(av0, pf0, o[i], 0, 0, 0);
            o[i] = __builtin_amdgcn_mfma_f32_16x16x32_bf16(av1, pf1, o[i], 0, 0, 0);
        }
        __builtin_amdgcn_s_setprio(0);
        cur ^= 1;
    }

    const float linv = 1.0f / accl[0];
    #pragma unroll
    for (int i = 0; i < 4; i++) {
        u16x4 ov;
        #pragma unroll
        for (int r = 0; r < 4; r++) ov[r] = f2bf_hw(o[i][r] * linv);
        *(u16x4*)(ctx + ((size_t)(q * 2 + b)) * 1024 + h * 64 + i * 16 + quad * 4) = ov;
    }
}

// ---------------- launcher (R5 workspace layout, proven) ----------------
// [0,6) bqkvT  [6,8) woT  [8,16) w1T  [16,24) w2T  [24,32) h1 (vT after QKV)
// [32,56) qkvB (xmid overlays [40,56) after attn)  [56,64) ctxB  [80,88) h2
// [88,120) partO -> actB.  W2 partials: p0 [0,16) p1 [24,40) p2 [56,72) p3 [72,88)
extern "C" void kernel_launch(void* const* d_in, const int* in_sizes, int n_in,
                              void* d_out, int out_size, void* d_ws, size_t ws_size,
                              hipStream_t stream)
{
    (void)in_sizes; (void)n_in; (void)out_size; (void)ws_size;
    const float* x  = (const float*)d_in[0];
    const float* g1 = (const float*)d_in[1];
    const float* g2 = (const float*)d_in[2];
    const float* Wq = (const float*)d_in[3];
    const float* Wk = (const float*)d_in[4];
    const float* Wv = (const float*)d_in[5];
    const float* Wo = (const float*)d_in[6];
    const float* W1 = (const float*)d_in[7];
    const float* W2 = (const float*)d_in[8];
    float* out = (float*)d_out;

    char* ws = (char*)d_ws;
    u16*   bqkvT = (u16*)(ws);
    u16*   woT   = (u16*)(ws + 6291456);
    u16*   w1T   = (u16*)(ws + 8388608);
    u16*   w2T   = (u16*)(ws + 16777216);
    u16*   h1    = (u16*)(ws + 25165824);
    u16*   qkvB  = (u16*)(ws + 33554432);
    u16*   vT    = (u16*)(ws + 25165824);         // reuses h1 (dead after QKV gemm)
    u16*   ctxB  = (u16*)(ws + 58720256);
    float* xmid  = (float*)(ws + 41943040);
    u16*   h2    = (u16*)(ws + 83886080);
    u16*   actB  = (u16*)(ws + 92274688);
    float* partO = (float*)(ws + 92274688);
    float* p0 = (float*)(ws);
    float* p1 = (float*)(ws + 25165824);
    float* p2 = (float*)(ws + 58720256);
    float* p3 = (float*)(ws + 75497472);

    // merged prep: QKV repack (768) + Wo^T (256) + W1^T (1024) + W2^T (1024) + rmsnorm (4096)
    prep_k<<<7168, 256, 0, stream>>>(Wq, Wk, Wv, Wo, W1, W2, x, g1,
                                     bqkvT, woT, w1T, w2T, h1);

    // QKV: 4096x3072x1024, 256² 8-phase (192 blocks)
    gemm8p_k<0><<<dim3(192, 1, 1), 512, 0, stream>>>(h1, bqkvT, qkvB,
                                                     nullptr, nullptr, nullptr, nullptr,
                                                     nullptr, 3072, 1024, 1024);
    vtrans_k<<<dim3(32, 32), 256, 0, stream>>>(qkvB, vT);
    attn_k<<<dim3(32, 32), 256, 0, stream>>>(qkvB, vT, ctxB);

    // Wo: N=1024 -> 128² split-K=2
    gemm_bt_k<3><<<dim3(8, 32, 2), 256, 0, stream>>>(ctxB, woT, nullptr, partO, nullptr,
                                                     4096, 1024, 1024, 512);
    addred_norm_k<<<4096, 256, 0, stream>>>(x, partO, partO + 4096 * 1024, g2, xmid, h2);

    // W1: 4096x4096x1024 (256 blocks, 1/CU)
    gemm8p_k<2><<<dim3(256, 1, 1), 512, 0, stream>>>(h2, w1T, actB,
                                                     nullptr, nullptr, nullptr, nullptr,
                                                     nullptr, 4096, 1024, 1024);
    // W2: 4096x1024x4096 split-K=4, z-aware XCD bands, residual fused into z==0 partial
    gemm8p_k<3><<<dim3(256, 1, 1), 512, 0, stream>>>(actB, w2T, nullptr,
                                                     p0, p1, p2, p3,
                                                     xmid, 1024, 4096, 1024);
    addredW_k<<<4096 * 1024 / 1024, 256, 0, stream>>>(p0, p1, p2, p3, out);
}

// Round 7
// 334.667 us; speedup vs baseline: 1.0028x; 1.0028x over previous
//
#include <hip/hip_runtime.h>

typedef unsigned short u16;
typedef __bf16 bf16x8 __attribute__((ext_vector_type(8)));
typedef u16 u16x8 __attribute__((ext_vector_type(8)));
typedef u16 u16x4 __attribute__((ext_vector_type(4)));
typedef float f32x4 __attribute__((ext_vector_type(4)));

__device__ __forceinline__ u16 f2bf(float f) {
    union { float f; unsigned int u; } x; x.f = f;
    unsigned int r = x.u + 0x7FFFu + ((x.u >> 16) & 1u);
    return (u16)(r >> 16);
}

__device__ __forceinline__ u16 f2bf_hw(float f) {
    union { __bf16 b; u16 u; } x; x.b = (__bf16)f; return x.u;
}

// async global -> LDS, 16B per lane. LDS dest is wave-uniform base + lane*16.
__device__ __forceinline__ void gload_lds16(const u16* g, u16* l) {
    __builtin_amdgcn_global_load_lds(
        (const __attribute__((address_space(1))) unsigned int*)g,
        (__attribute__((address_space(3))) unsigned int*)l, 16, 0, 0);
}

// ---------------- merged prep: QKV repack + Wo/W1/W2 transpose + rmsnorm ----------------

__device__ __forceinline__ void transT_body(
    const float* __restrict__ in, u16* __restrict__ out, int R, int C,
    int bx, int by, float T[64][65], int tid)
{
    const int r0 = bx * 64, c0 = by * 64;
    const int tr = tid >> 4;
    const int tc = (tid & 15) * 4;
    #pragma unroll
    for (int k = 0; k < 4; k++) {
        f32x4 v = *(const f32x4*)(in + (size_t)(c0 + 16 * k + tr) * R + r0 + tc);
        T[16 * k + tr][tc]     = v[0];
        T[16 * k + tr][tc + 1] = v[1];
        T[16 * k + tr][tc + 2] = v[2];
        T[16 * k + tr][tc + 3] = v[3];
    }
    __syncthreads();
    #pragma unroll
    for (int k = 0; k < 4; k++) {
        const int rl = 16 * k + tr;
        u16x4 o;
        #pragma unroll
        for (int i = 0; i < 4; i++) o[i] = f2bf(T[tc + i][rl]);
        *(u16x4*)(out + (size_t)(r0 + rl) * C + c0 + tc) = o;
    }
}

__global__ __launch_bounds__(256) void prep_k(
    const float* __restrict__ Wq, const float* __restrict__ Wk,
    const float* __restrict__ Wv, const float* __restrict__ Wo,
    const float* __restrict__ W1, const float* __restrict__ W2,
    const float* __restrict__ x, const float* __restrict__ g1,
    u16* __restrict__ bqkvT, u16* __restrict__ woT,
    u16* __restrict__ w1T, u16* __restrict__ w2T, u16* __restrict__ h1)
{
    __shared__ float T[64][65];
    const int id = blockIdx.x;
    const int tid = threadIdx.x;

    if (id < 768) {
        const int bx = id & 15, y = id >> 4;
        const int d0 = bx * 64;
        const int wsel = y >> 4, h = y & 15;
        const float* W = (wsel == 0) ? Wq : (wsel == 1) ? Wk : Wv;
        const float scale = (wsel == 0) ? 0.125f * 1.44269504088896f : 1.0f;
        const int tr = tid >> 4;
        const int tc = (tid & 15) * 4;
        #pragma unroll
        for (int k = 0; k < 4; k++) {
            f32x4 v = *(const f32x4*)(W + (size_t)h * 65536 + (size_t)(d0 + 16 * k + tr) * 64 + tc);
            T[16 * k + tr][tc]     = v[0];
            T[16 * k + tr][tc + 1] = v[1];
            T[16 * k + tr][tc + 2] = v[2];
            T[16 * k + tr][tc + 3] = v[3];
        }
        __syncthreads();
        #pragma unroll
        for (int k = 0; k < 4; k++) {
            const int kk = 16 * k + tr;
            u16x4 o;
            #pragma unroll
            for (int i = 0; i < 4; i++) o[i] = f2bf(T[tc + i][kk] * scale);
            *(u16x4*)(bqkvT + (size_t)(wsel * 1024 + h * 64 + kk) * 1024 + d0 + tc) = o;
        }
    } else if (id < 1024) {
        const int id2 = id - 768;
        transT_body(Wo, woT, 1024, 1024, id2 & 15, id2 >> 4, T, tid);
    } else if (id < 2048) {
        const int id3 = id - 1024;
        transT_body(W1, w1T, 4096, 1024, id3 & 63, id3 >> 6, T, tid);
    } else if (id < 3072) {
        const int id4 = id - 2048;
        transT_body(W2, w2T, 1024, 4096, id4 & 15, id4 >> 4, T, tid);
    } else {
        const int row = id - 3072;
        const float* xr = x + (size_t)row * 1024;
        f32x4 v = *(const f32x4*)(xr + tid * 4);
        float ss = v[0] * v[0] + v[1] * v[1] + v[2] * v[2] + v[3] * v[3];
        #pragma unroll
        for (int off = 32; off > 0; off >>= 1) ss += __shfl_down(ss, off);
        float* red = &T[0][0];
        if ((tid & 63) == 0) red[tid >> 6] = ss;
        __syncthreads();
        float sum = red[0] + red[1] + red[2] + red[3];
        float rinv = rsqrtf(sum * (1.0f / 1024.0f) + 1e-6f);
        f32x4 gv = *(const f32x4*)(g1 + tid * 4);
        u16x4 o;
        #pragma unroll
        for (int i = 0; i < 4; i++) o[i] = f2bf(v[i] * gv[i] * rinv);
        *(u16x4*)(h1 + (size_t)row * 1024 + tid * 4) = o;
    }
}

// standalone rmsnorm: out = rmsnorm(x)*g, bf16
__global__ __launch_bounds__(256) void rmsnorm_k(
    const float* __restrict__ x, const float* __restrict__ g, u16* __restrict__ out)
{
    const int row = blockIdx.x;
    const int tid = threadIdx.x;
    const float* xr = x + (size_t)row * 1024;
    f32x4 v = *(const f32x4*)(xr + tid * 4);
    float ss = v[0] * v[0] + v[1] * v[1] + v[2] * v[2] + v[3] * v[3];
    #pragma unroll
    for (int off = 32; off > 0; off >>= 1) ss += __shfl_down(ss, off);
    __shared__ float red[4];
    if ((tid & 63) == 0) red[tid >> 6] = ss;
    __syncthreads();
    float sum = red[0] + red[1] + red[2] + red[3];
    float rinv = rsqrtf(sum * (1.0f / 1024.0f) + 1e-6f);
    f32x4 gv = *(const f32x4*)(g + tid * 4);
    u16x4 o;
    #pragma unroll
    for (int i = 0; i < 4; i++) o[i] = f2bf(v[i] * gv[i] * rinv);
    *(u16x4*)(out + (size_t)row * 1024 + tid * 4) = o;
}

// V^T: vT[(b*16+h)*64 + d][s] = qkvB[s*2+b][2048 + h*64 + d]
__global__ __launch_bounds__(256) void vtrans_k(const u16* __restrict__ qkv, u16* __restrict__ vT)
{
    __shared__ u16 T[64][72];
    const int bh = blockIdx.x, b = bh >> 4, h = bh & 15;
    const int s0 = blockIdx.y * 64;
    const int tid = threadIdx.x;
    const int r = tid >> 2, c0 = (tid & 3) * 16;
    const u16* src = qkv + ((size_t)((s0 + r) * 2 + b)) * 3072 + 2048 + h * 64 + c0;
    *(u16x8*)&T[r][c0] = *(const u16x8*)src;
    *(u16x8*)&T[r][c0 + 8] = *(const u16x8*)(src + 8);
    __syncthreads();
    u16x8 o0, o1;
    #pragma unroll
    for (int i = 0; i < 8; i++) o0[i] = T[c0 + i][r];
    #pragma unroll
    for (int i = 0; i < 8; i++) o1[i] = T[c0 + 8 + i][r];
    u16* dst = vT + (size_t)(bh * 64 + r) * 2048 + s0 + c0;
    *(u16x8*)dst = o0;
    *(u16x8*)(dst + 8) = o1;
}

// out = a0 + a1 + a2 + a3 (a0 already includes the residual, fused in W2 z==0)
__global__ __launch_bounds__(256) void addredW_k(
    const float* __restrict__ a0, const float* __restrict__ a1,
    const float* __restrict__ a2, const float* __restrict__ a3,
    float* __restrict__ out)
{
    int i = (blockIdx.x * 256 + threadIdx.x) * 4;
    f32x4 v = *(const f32x4*)(a0 + i);
    v = v + *(const f32x4*)(a1 + i);
    v = v + *(const f32x4*)(a2 + i);
    v = v + *(const f32x4*)(a3 + i);
    *(f32x4*)(out + i) = v;
}

// ---------------- GEMM (legacy 128x128, kept for Wo: dense, MODE 1 fuses residual) ----
template <int MODE>
__global__ __launch_bounds__(256) void gemm_bt_k(
    const u16* __restrict__ A, const u16* __restrict__ BT,
    u16* __restrict__ outB, float* __restrict__ outF, const float* __restrict__ res,
    int M, int N, int K, int klen)
{
    __shared__ u16 As[2][128 * 64];
    __shared__ u16 Bs[2][128 * 64];
    const int tid = threadIdx.x;
    const int lane = tid & 63, w = tid >> 6;
    const int wm = w >> 1, wn = w & 1;
    const int quad = lane >> 4, l15 = lane & 15;
    const int bid = blockIdx.x + gridDim.x * blockIdx.y;
    const int bj = bid >> 3;
    const int m0 = ((bid & 7) * 4 + (bj & 3)) * 128;
    const int n0 = (bj >> 2) * 128;
    const int kbeg = blockIdx.z * klen;

    f32x4 acc[4][4] = {};

    const int srow = (w << 3) + (lane >> 3);
    const int swz = ((lane & 7) ^ (lane >> 3)) << 3;
    const u16* aA = A + (size_t)(m0 + srow) * K + kbeg + swz;
    const u16* aB = BT + (size_t)(n0 + srow) * K + kbeg + swz;
    const int wo = w * 512;
    const int rsw = (l15 & 7) << 3;

    #pragma unroll
    for (int c = 0; c < 4; c++) {
        gload_lds16(aA + (size_t)(c * 32) * K, &As[0][0] + c * 2048 + wo);
        gload_lds16(aB + (size_t)(c * 32) * K, &Bs[0][0] + c * 2048 + wo);
    }

    int cur = 0;
    for (int k0 = 0; k0 < klen; k0 += 64) {
        __syncthreads();
        if (k0 + 64 < klen) {
            #pragma unroll
            for (int c = 0; c < 4; c++) {
                gload_lds16(aA + (size_t)(c * 32) * K + k0 + 64, &As[cur ^ 1][0] + c * 2048 + wo);
                gload_lds16(aB + (size_t)(c * 32) * K + k0 + 64, &Bs[cur ^ 1][0] + c * 2048 + wo);
            }
        }
        const u16* AB = &As[cur][0];
        const u16* BB = &Bs[cur][0];
        #pragma unroll
        for (int kh = 0; kh < 2; kh++) {
            const int cb = ((kh * 4 + quad) << 3);
            bf16x8 af[4], bfr[4];
            #pragma unroll
            for (int i = 0; i < 4; i++)
                af[i] = *(const bf16x8*)(AB + (wm * 64 + i * 16 + l15) * 64 + (cb ^ rsw));
            #pragma unroll
            for (int j = 0; j < 4; j++)
                bfr[j] = *(const bf16x8*)(BB + (wn * 64 + j * 16 + l15) * 64 + (cb ^ rsw));
            #pragma unroll
            for (int i = 0; i < 4; i++)
                #pragma unroll
                for (int j = 0; j < 4; j++)
                    acc[i][j] = __builtin_amdgcn_mfma_f32_16x16x32_bf16(af[i], bfr[j], acc[i][j], 0, 0, 0);
        }
        cur ^= 1;
    }

    float* outFz = (MODE == 3) ? outF + (size_t)blockIdx.z * M * N : outF;
    #pragma unroll
    for (int i = 0; i < 4; i++) {
        const int row = m0 + wm * 64 + i * 16 + quad * 4;
        #pragma unroll
        for (int j = 0; j < 4; j++) {
            const int col = n0 + wn * 64 + j * 16 + l15;
            #pragma unroll
            for (int r = 0; r < 4; r++) {
                const size_t idx = (size_t)(row + r) * N + col;
                float v = acc[i][j][r];
                if (MODE == 0) {
                    outB[idx] = f2bf_hw(v);
                } else if (MODE == 1) {
                    outF[idx] = res[idx] + v;
                } else if (MODE == 2) {
                    float e = exp2f(v * -1.44269504088896f);
                    outB[idx] = f2bf_hw(v * __builtin_amdgcn_rcpf(1.0f + e));
                } else {
                    outFz[idx] = v;
                }
            }
        }
    }
}

// ---------------- GEMM 256x256 8-phase (R5 schedule; R6's z-band map REVERTED) ----------
// MODE 3 keeps blockIdx.z split-K with the generic XCD band map (R5, measured 47us);
// z==0 blocks fuse the residual (po = v + res) so the final reduce is 4 streams.
#define MMQ(FH, AS, BS) \
    { _Pragma("unroll") \
      for (int i_ = 0; i_ < 4; i_++) { \
        acc[(FH)*4+i_][0] = __builtin_amdgcn_mfma_f32_16x16x32_bf16(AS[i_], BS[0], acc[(FH)*4+i_][0], 0, 0, 0); \
        acc[(FH)*4+i_][1] = __builtin_amdgcn_mfma_f32_16x16x32_bf16(AS[i_], BS[1], acc[(FH)*4+i_][1], 0, 0, 0); \
        acc[(FH)*4+i_][2] = __builtin_amdgcn_mfma_f32_16x16x32_bf16(AS[i_], BS[2], acc[(FH)*4+i_][2], 0, 0, 0); \
        acc[(FH)*4+i_][3] = __builtin_amdgcn_mfma_f32_16x16x32_bf16(AS[i_], BS[3], acc[(FH)*4+i_][3], 0, 0, 0); \
      } }

#define SBAR   __builtin_amdgcn_s_barrier()
#define FENCE  asm volatile("" ::: "memory")

template <int MODE>
__global__ __launch_bounds__(512, 2) void gemm8p_k(
    const u16* __restrict__ A, const u16* __restrict__ BT,
    u16* __restrict__ outB, float* __restrict__ q0, float* __restrict__ q1,
    float* __restrict__ q2, float* __restrict__ q3, const float* __restrict__ res,
    int N, int K, int klen)
{
    __shared__ u16 sm[65536];          // 128 KiB: [buf][A/B][kh][8192]
    const int tid = threadIdx.x;
    const int lane = tid & 63, w = tid >> 6;
    const int l15 = lane & 15, quad = lane >> 4;
    const int wm = w >> 2, wn = w & 3;

    const int nwg = gridDim.x;
    const int bid = blockIdx.x;
    const int s = (bid & 7) * (nwg >> 3) + (bid >> 3);   // XCD-contiguous bands
    const int m0 = (s & 15) * 256;                       // M = 4096 fixed
    const int n0 = (s >> 4) * 256;
    const int zz = blockIdx.z;
    const int kbeg = zz * klen;
    const int nT = klen >> 6;

    const int srow = w * 16 + (lane >> 2);
    const int scol = (((lane & 3) ^ ((lane >> 3) & 3)) << 3);  // inverse swizzle on source
    const u16* gA = A + (size_t)(m0 + srow) * K + kbeg + scol;
    const u16* gB = BT + (size_t)(n0 + srow) * K + kbeg + scol;
    const size_t cstep = (size_t)128 * K;

    const int rswz = ((quad ^ ((l15 >> 1) & 3)) << 3);
    const int raoff = (wm * 128 + l15) * 32 + rswz;
    const int rboff = (wn * 64 + l15) * 32 + rswz;

    f32x4 acc[8][4] = {};

    auto stA = [&](int t, int kh) {
        u16* d = sm + (t & 1) * 32768 + kh * 8192 + w * 512;
        const u16* g = gA + (size_t)(t * 64 + kh * 32);
        gload_lds16(g, d);
        gload_lds16(g + cstep, d + 4096);
    };
    auto stB = [&](int t, int kh) {
        u16* d = sm + (t & 1) * 32768 + 16384 + kh * 8192 + w * 512;
        const u16* g = gB + (size_t)(t * 64 + kh * 32);
        gload_lds16(g, d);
        gload_lds16(g + cstep, d + 4096);
    };
    auto rdB = [&](int buf, int kh, bf16x8* b) {
        const u16* p = sm + buf * 32768 + 16384 + kh * 8192 + rboff;
        b[0] = *(const bf16x8*)(p);
        b[1] = *(const bf16x8*)(p + 512);
        b[2] = *(const bf16x8*)(p + 1024);
        b[3] = *(const bf16x8*)(p + 1536);
    };
    auto rdA = [&](int buf, int kh, int fh, bf16x8* a) {
        const u16* p = sm + buf * 32768 + kh * 8192 + fh * 2048 + raoff;
        a[0] = *(const bf16x8*)(p);
        a[1] = *(const bf16x8*)(p + 512);
        a[2] = *(const bf16x8*)(p + 1024);
        a[3] = *(const bf16x8*)(p + 1536);
    };

    // prologue: tile0 (4 halves) + tile1 kh0; drain tile0 (8 oldest loads)
    stA(0, 0); stB(0, 0); stA(0, 1); stB(0, 1);
    if (nT > 1) {
        stA(1, 0); stB(1, 0);
        asm volatile("s_waitcnt vmcnt(4)" ::: "memory");
    } else {
        asm volatile("s_waitcnt vmcnt(0)" ::: "memory");
    }
    SBAR; FENCE;

    for (int t = 0; t < nT; t++) {
        const int buf = t & 1;
        bf16x8 a[4], b[4];
        // ph1: fh0 x kh0
        rdA(buf, 0, 0, a); rdB(buf, 0, b);
        if (t + 1 < nT) stA(t + 1, 1);
        SBAR; FENCE;
        __builtin_amdgcn_s_setprio(1);
        MMQ(0, a, b)
        __builtin_amdgcn_s_setprio(0);
        SBAR; FENCE;
        // ph2: fh1 x kh0 (reuse b)
        rdA(buf, 0, 1, a);
        if (t + 1 < nT) stB(t + 1, 1);
        SBAR; FENCE;
        __builtin_amdgcn_s_setprio(1);
        MMQ(1, a, b)
        __builtin_amdgcn_s_setprio(0);
        SBAR; FENCE;
        // ph3: fh0 x kh1
        rdA(buf, 1, 0, a); rdB(buf, 1, b);
        if (t + 2 < nT) stA(t + 2, 0);
        SBAR; FENCE;
        __builtin_amdgcn_s_setprio(1);
        MMQ(0, a, b)
        __builtin_amdgcn_s_setprio(0);
        SBAR; FENCE;
        // ph4: fh1 x kh1 ; counted vmcnt once per tile
        rdA(buf, 1, 1, a);
        if (t + 2 < nT) {
            stB(t + 2, 0);
            asm volatile("s_waitcnt vmcnt(4)" ::: "memory");
        } else {
            asm volatile("s_waitcnt vmcnt(0)" ::: "memory");
        }
        SBAR; FENCE;
        __builtin_amdgcn_s_setprio(1);
        MMQ(1, a, b)
        __builtin_amdgcn_s_setprio(0);
        SBAR; FENCE;
    }

    float* po = nullptr;
    if (MODE == 3)
        po = (zz == 0) ? q0 : (zz == 1) ? q1 : (zz == 2) ? q2 : q3;
    #pragma unroll
    for (int mf = 0; mf < 8; mf++) {
        const int row = m0 + wm * 128 + mf * 16 + quad * 4;
        #pragma unroll
        for (int nf = 0; nf < 4; nf++) {
            const int col = n0 + wn * 64 + nf * 16 + l15;
            #pragma unroll
            for (int r = 0; r < 4; r++) {
                const size_t idx = (size_t)(row + r) * N + col;
                const float v = acc[mf][nf][r];
                if (MODE == 0) {
                    outB[idx] = f2bf_hw(v);
                } else if (MODE == 2) {
                    float e = exp2f(v * -1.44269504088896f);
                    outB[idx] = f2bf_hw(v * __builtin_amdgcn_rcpf(1.0f + e));
                } else {
                    po[idx] = (zz == 0) ? v + res[idx] : v;
                }
            }
        }
    }
}

// ---------------- flash attention (swapped QK^T, in-register softmax) ----------------
__global__ __launch_bounds__(256, 4) void attn_k(const u16* __restrict__ qkv,
                                                 const u16* __restrict__ vT,
                                                 u16* __restrict__ ctx)
{
    const int bh = blockIdx.x;
    const int qt = 31 - (int)blockIdx.y;
    const int b = bh >> 4, h = bh & 15;
    const int q0 = qt * 64;
    const int tid = threadIdx.x;
    const int lane = tid & 63, w = tid >> 6;
    const int quad = lane >> 4, l15 = lane & 15;

    __shared__ u16 Ks[2][4096];
    __shared__ u16 Vs[2][4096];

    const int q = q0 + 16 * w + l15;
    const u16* qrow = qkv + ((size_t)(q * 2 + b)) * 3072 + h * 64;
    const bf16x8 aq0 = *(const bf16x8*)(qrow + quad * 8);
    const bf16x8 aq1 = *(const bf16x8*)(qrow + 32 + quad * 8);

    bf16x8 ones;
    #pragma unroll
    for (int i = 0; i < 8; i++) ones[i] = (__bf16)1.0f;

    const int kr = (w << 3) + (lane >> 3);
    const int swz = ((lane & 7) ^ (lane >> 3)) << 3;
    const int ldsoff = w * 512;
    const u16* kbase0 = qkv + ((size_t)(kr * 2 + b)) * 3072 + 1024 + h * 64 + swz;
    const u16* kbase1 = kbase0 + (size_t)32 * 2 * 3072;
    const u16* vrow0 = vT + (size_t)(bh * 64 + kr) * 2048 + swz;
    const u16* vrow1 = vrow0 + (size_t)32 * 2048;

    const int sl = (l15 & 3) | ((l15 & 4) << 1) | ((l15 & 8) >> 1);
    const int rswk = (sl & 7) << 3;
    const int rswv = (l15 & 7) << 3;
    const int sq = ((quad & 1) << 1) | (quad >> 1);
    const int qloc = 16 * w + l15;

    f32x4 o[4] = {};
    f32x4 accl = {};

    gload_lds16(kbase0, &Ks[0][0] + ldsoff);
    gload_lds16(kbase1, &Ks[0][0] + 2048 + ldsoff);
    gload_lds16(vrow0, &Vs[0][0] + ldsoff);
    gload_lds16(vrow1, &Vs[0][0] + 2048 + ldsoff);

    int cur = 0;
    for (int t0 = 0; t0 <= q0; t0 += 64) {
        __syncthreads();
        if (t0 + 64 <= q0) {
            const size_t go = (size_t)(t0 + 64) * 2 * 3072;
            u16* KB = &Ks[cur ^ 1][0];
            u16* VB = &Vs[cur ^ 1][0];
            gload_lds16(kbase0 + go, KB + ldsoff);
            gload_lds16(kbase1 + go, KB + 2048 + ldsoff);
            gload_lds16(vrow0 + (t0 + 64), VB + ldsoff);
            gload_lds16(vrow1 + (t0 + 64), VB + 2048 + ldsoff);
        }
        const u16* KB = &Ks[cur][0];
        const u16* VB = &Vs[cur][0];

        f32x4 s[4];
        __builtin_amdgcn_s_setprio(1);
        #pragma unroll
        for (int tg = 0; tg < 4; tg++) {
            const u16* kb = KB + (16 * tg + sl) * 64;
            bf16x8 ak0 = *(const bf16x8*)(kb + ((quad << 3) ^ rswk));
            bf16x8 ak1 = *(const bf16x8*)(kb + (((quad + 4) << 3) ^ rswk));
            f32x4 c = {};
            c = __builtin_amdgcn_mfma_f32_16x16x32_bf16(ak0, aq0, c, 0, 0, 0);
            c = __builtin_amdgcn_mfma_f32_16x16x32_bf16(ak1, aq1, c, 0, 0, 0);
            s[tg] = c;
        }
        __builtin_amdgcn_s_setprio(0);

        if (t0 == q0) {
            #pragma unroll
            for (int tg = 0; tg < 4; tg++)
                #pragma unroll
                for (int r = 0; r < 4; r++)
                    if ((16 * tg + 4 * sq + r) > qloc) s[tg][r] = -1e30f;
        }

        unsigned dd[4][2];
        #pragma unroll
        for (int tg = 0; tg < 4; tg++) {
            float e0 = exp2f(s[tg][0]), e1 = exp2f(s[tg][1]);
            float e2 = exp2f(s[tg][2]), e3 = exp2f(s[tg][3]);
            asm("v_cvt_pk_bf16_f32 %0, %1, %2" : "=v"(dd[tg][0]) : "v"(e0), "v"(e1));
            asm("v_cvt_pk_bf16_f32 %0, %1, %2" : "=v"(dd[tg][1]) : "v"(e2), "v"(e3));
        }
        unsigned x0 = dd[0][0], y0 = dd[1][0];
        asm volatile("v_permlane32_swap_b32 %0, %1" : "+v"(x0), "+v"(y0));
        unsigned x1 = dd[0][1], y1 = dd[1][1];
        asm volatile("v_permlane32_swap_b32 %0, %1" : "+v"(x1), "+v"(y1));
        unsigned x2 = dd[2][0], y2 = dd[3][0];
        asm volatile("v_permlane32_swap_b32 %0, %1" : "+v"(x2), "+v"(y2));
        unsigned x3 = dd[2][1], y3 = dd[3][1];
        asm volatile("v_permlane32_swap_b32 %0, %1" : "+v"(x3), "+v"(y3));

        union { unsigned u[4]; bf16x8 v; } pu0, pu1;
        pu0.u[0] = x0; pu0.u[1] = x1; pu0.u[2] = y0; pu0.u[3] = y1;
        pu1.u[0] = x2; pu1.u[1] = x3; pu1.u[2] = y2; pu1.u[3] = y3;
        const bf16x8 pf0 = pu0.v, pf1 = pu1.v;

        __builtin_amdgcn_s_setprio(1);
        accl = __builtin_amdgcn_mfma_f32_16x16x32_bf16(ones, pf0, accl, 0, 0, 0);
        accl = __builtin_amdgcn_mfma_f32_16x16x32_bf16(ones, pf1, accl, 0, 0, 0);
        #pragma unroll
        for (int i = 0; i < 4; i++) {
            const u16* vb = VB + (i * 16 + l15) * 64;
            bf16x8 av0 = *(const bf16x8*)(vb + ((quad << 3) ^ rswv));
            bf16x8 av1 = *(const bf16x8*)(vb + (((quad + 4) << 3) ^ rswv));
            o[i] = __builtin_amdgcn_mfma_f32_16x16x32_bf16(av0, pf0, o[i], 0, 0, 0);
            o[i] = __builtin_amdgcn_mfma_f32_16x16x32_bf16(av1, pf1, o[i], 0, 0, 0);
        }
        __builtin_amdgcn_s_setprio(0);
        cur ^= 1;
    }

    const float linv = 1.0f / accl[0];
    #pragma unroll
    for (int i = 0; i < 4; i++) {
        u16x4 ov;
        #pragma unroll
        for (int r = 0; r < 4; r++) ov[r] = f2bf_hw(o[i][r] * linv);
        *(u16x4*)(ctx + ((size_t)(q * 2 + b)) * 1024 + h * 64 + i * 16 + quad * 4) = ov;
    }
}

// ---------------- launcher ----------------
// [0,6) bqkvT  [6,8) woT  [8,16) w1T  [16,24) w2T  [24,32) h1 (vT after QKV)
// [32,56) qkvB (xmid overlays [40,56) after attn)  [56,64) ctxB  [80,88) h2
// [88,120) actB.  W2 partials: p0 [0,16) p1 [24,40) p2 [56,72) p3 [72,88)
extern "C" void kernel_launch(void* const* d_in, const int* in_sizes, int n_in,
                              void* d_out, int out_size, void* d_ws, size_t ws_size,
                              hipStream_t stream)
{
    (void)in_sizes; (void)n_in; (void)out_size; (void)ws_size;
    const float* x  = (const float*)d_in[0];
    const float* g1 = (const float*)d_in[1];
    const float* g2 = (const float*)d_in[2];
    const float* Wq = (const float*)d_in[3];
    const float* Wk = (const float*)d_in[4];
    const float* Wv = (const float*)d_in[5];
    const float* Wo = (const float*)d_in[6];
    const float* W1 = (const float*)d_in[7];
    const float* W2 = (const float*)d_in[8];
    float* out = (float*)d_out;

    char* ws = (char*)d_ws;
    u16*   bqkvT = (u16*)(ws);
    u16*   woT   = (u16*)(ws + 6291456);
    u16*   w1T   = (u16*)(ws + 8388608);
    u16*   w2T   = (u16*)(ws + 16777216);
    u16*   h1    = (u16*)(ws + 25165824);
    u16*   qkvB  = (u16*)(ws + 33554432);
    u16*   vT    = (u16*)(ws + 25165824);         // reuses h1 (dead after QKV gemm)
    u16*   ctxB  = (u16*)(ws + 58720256);
    float* xmid  = (float*)(ws + 41943040);
    u16*   h2    = (u16*)(ws + 83886080);
    u16*   actB  = (u16*)(ws + 92274688);
    float* p0 = (float*)(ws);
    float* p1 = (float*)(ws + 25165824);
    float* p2 = (float*)(ws + 58720256);
    float* p3 = (float*)(ws + 75497472);

    // merged prep: QKV repack (768) + Wo^T (256) + W1^T (1024) + W2^T (1024) + rmsnorm (4096)
    prep_k<<<7168, 256, 0, stream>>>(Wq, Wk, Wv, Wo, W1, W2, x, g1,
                                     bqkvT, woT, w1T, w2T, h1);

    // QKV: 4096x3072x1024, 256² 8-phase (192 blocks)
    gemm8p_k<0><<<dim3(192, 1, 1), 512, 0, stream>>>(h1, bqkvT, qkvB,
                                                     nullptr, nullptr, nullptr, nullptr,
                                                     nullptr, 3072, 1024, 1024);
    vtrans_k<<<dim3(32, 32), 256, 0, stream>>>(qkvB, vT);
    attn_k<<<dim3(32, 32), 256, 0, stream>>>(qkvB, vT, ctxB);

    // Wo: dense 128² (256 blocks), residual fused -> xmid = x + ctx@Wo (no partials)
    gemm_bt_k<1><<<dim3(8, 32), 256, 0, stream>>>(ctxB, woT, nullptr, xmid, x,
                                                  4096, 1024, 1024, 1024);
    // h2 = rmsnorm(xmid)*g2
    rmsnorm_k<<<4096, 256, 0, stream>>>(xmid, g2, h2);

    // W1: 4096x4096x1024 (256 blocks, 1/CU)
    gemm8p_k<2><<<dim3(256, 1, 1), 512, 0, stream>>>(h2, w1T, actB,
                                                     nullptr, nullptr, nullptr, nullptr,
                                                     nullptr, 4096, 1024, 1024);
    // W2: 4096x1024x4096 split-K=4 (R5 mapping, dim3(64,1,4)); residual fused into z==0
    gemm8p_k<3><<<dim3(64, 1, 4), 512, 0, stream>>>(actB, w2T, nullptr,
                                                    p0, p1, p2, p3,
                                                    xmid, 1024, 4096, 1024);
    addredW_k<<<4096 * 1024 / 1024, 256, 0, stream>>>(p0, p1, p2, p3, out);
}

// Round 8
// 315.400 us; speedup vs baseline: 1.0641x; 1.0611x over previous
//
#include <hip/hip_runtime.h>

typedef unsigned short u16;
typedef __bf16 bf16x8 __attribute__((ext_vector_type(8)));
typedef u16 u16x8 __attribute__((ext_vector_type(8)));
typedef u16 u16x4 __attribute__((ext_vector_type(4)));
typedef float f32x4 __attribute__((ext_vector_type(4)));

__device__ __forceinline__ u16 f2bf(float f) {
    union { float f; unsigned int u; } x; x.f = f;
    unsigned int r = x.u + 0x7FFFu + ((x.u >> 16) & 1u);
    return (u16)(r >> 16);
}

__device__ __forceinline__ u16 f2bf_hw(float f) {
    union { __bf16 b; u16 u; } x; x.b = (__bf16)f; return x.u;
}

// async global -> LDS, 16B per lane. LDS dest is wave-uniform base + lane*16.
__device__ __forceinline__ void gload_lds16(const u16* g, u16* l) {
    __builtin_amdgcn_global_load_lds(
        (const __attribute__((address_space(1))) unsigned int*)g,
        (__attribute__((address_space(3))) unsigned int*)l, 16, 0, 0);
}

// ---------------- merged prep: QKV repack + Wo/W1/W2 transpose + rmsnorm ----------------

__device__ __forceinline__ void transT_body(
    const float* __restrict__ in, u16* __restrict__ out, int R, int C,
    int bx, int by, float T[64][65], int tid)
{
    const int r0 = bx * 64, c0 = by * 64;
    const int tr = tid >> 4;
    const int tc = (tid & 15) * 4;
    #pragma unroll
    for (int k = 0; k < 4; k++) {
        f32x4 v = *(const f32x4*)(in + (size_t)(c0 + 16 * k + tr) * R + r0 + tc);
        T[16 * k + tr][tc]     = v[0];
        T[16 * k + tr][tc + 1] = v[1];
        T[16 * k + tr][tc + 2] = v[2];
        T[16 * k + tr][tc + 3] = v[3];
    }
    __syncthreads();
    #pragma unroll
    for (int k = 0; k < 4; k++) {
        const int rl = 16 * k + tr;
        u16x4 o;
        #pragma unroll
        for (int i = 0; i < 4; i++) o[i] = f2bf(T[tc + i][rl]);
        *(u16x4*)(out + (size_t)(r0 + rl) * C + c0 + tc) = o;
    }
}

__global__ __launch_bounds__(256) void prep_k(
    const float* __restrict__ Wq, const float* __restrict__ Wk,
    const float* __restrict__ Wv, const float* __restrict__ Wo,
    const float* __restrict__ W1, const float* __restrict__ W2,
    const float* __restrict__ x, const float* __restrict__ g1,
    u16* __restrict__ bqkvT, u16* __restrict__ woT,
    u16* __restrict__ w1T, u16* __restrict__ w2T, u16* __restrict__ h1)
{
    __shared__ float T[64][65];
    const int id = blockIdx.x;
    const int tid = threadIdx.x;

    if (id < 768) {
        const int bx = id & 15, y = id >> 4;
        const int d0 = bx * 64;
        const int wsel = y >> 4, h = y & 15;
        const float* W = (wsel == 0) ? Wq : (wsel == 1) ? Wk : Wv;
        const float scale = (wsel == 0) ? 0.125f * 1.44269504088896f : 1.0f;
        const int tr = tid >> 4;
        const int tc = (tid & 15) * 4;
        #pragma unroll
        for (int k = 0; k < 4; k++) {
            f32x4 v = *(const f32x4*)(W + (size_t)h * 65536 + (size_t)(d0 + 16 * k + tr) * 64 + tc);
            T[16 * k + tr][tc]     = v[0];
            T[16 * k + tr][tc + 1] = v[1];
            T[16 * k + tr][tc + 2] = v[2];
            T[16 * k + tr][tc + 3] = v[3];
        }
        __syncthreads();
        #pragma unroll
        for (int k = 0; k < 4; k++) {
            const int kk = 16 * k + tr;
            u16x4 o;
            #pragma unroll
            for (int i = 0; i < 4; i++) o[i] = f2bf(T[tc + i][kk] * scale);
            *(u16x4*)(bqkvT + (size_t)(wsel * 1024 + h * 64 + kk) * 1024 + d0 + tc) = o;
        }
    } else if (id < 1024) {
        const int id2 = id - 768;
        transT_body(Wo, woT, 1024, 1024, id2 & 15, id2 >> 4, T, tid);
    } else if (id < 2048) {
        const int id3 = id - 1024;
        transT_body(W1, w1T, 4096, 1024, id3 & 63, id3 >> 6, T, tid);
    } else if (id < 3072) {
        const int id4 = id - 2048;
        transT_body(W2, w2T, 1024, 4096, id4 & 15, id4 >> 4, T, tid);
    } else {
        const int row = id - 3072;
        const float* xr = x + (size_t)row * 1024;
        f32x4 v = *(const f32x4*)(xr + tid * 4);
        float ss = v[0] * v[0] + v[1] * v[1] + v[2] * v[2] + v[3] * v[3];
        #pragma unroll
        for (int off = 32; off > 0; off >>= 1) ss += __shfl_down(ss, off);
        float* red = &T[0][0];
        if ((tid & 63) == 0) red[tid >> 6] = ss;
        __syncthreads();
        float sum = red[0] + red[1] + red[2] + red[3];
        float rinv = rsqrtf(sum * (1.0f / 1024.0f) + 1e-6f);
        f32x4 gv = *(const f32x4*)(g1 + tid * 4);
        u16x4 o;
        #pragma unroll
        for (int i = 0; i < 4; i++) o[i] = f2bf(v[i] * gv[i] * rinv);
        *(u16x4*)(h1 + (size_t)row * 1024 + tid * 4) = o;
    }
}

// V^T: vT[(b*16+h)*64 + d][s] = qkvB[s*2+b][2048 + h*64 + d]
__global__ __launch_bounds__(256) void vtrans_k(const u16* __restrict__ qkv, u16* __restrict__ vT)
{
    __shared__ u16 T[64][72];
    const int bh = blockIdx.x, b = bh >> 4, h = bh & 15;
    const int s0 = blockIdx.y * 64;
    const int tid = threadIdx.x;
    const int r = tid >> 2, c0 = (tid & 3) * 16;
    const u16* src = qkv + ((size_t)((s0 + r) * 2 + b)) * 3072 + 2048 + h * 64 + c0;
    *(u16x8*)&T[r][c0] = *(const u16x8*)src;
    *(u16x8*)&T[r][c0 + 8] = *(const u16x8*)(src + 8);
    __syncthreads();
    u16x8 o0, o1;
    #pragma unroll
    for (int i = 0; i < 8; i++) o0[i] = T[c0 + i][r];
    #pragma unroll
    for (int i = 0; i < 8; i++) o1[i] = T[c0 + 8 + i][r];
    u16* dst = vT + (size_t)(bh * 64 + r) * 2048 + s0 + c0;
    *(u16x8*)dst = o0;
    *(u16x8*)(dst + 8) = o1;
}

// xout = res + p0 + p1 ; hout = rmsnorm(xout)*g   (block = one 1024-wide row)
__global__ __launch_bounds__(256) void addred_norm_k(
    const float* __restrict__ res, const float* __restrict__ p0,
    const float* __restrict__ p1, const float* __restrict__ g,
    float* __restrict__ xout, u16* __restrict__ hout)
{
    const int row = blockIdx.x;
    const int tid = threadIdx.x;
    const size_t base = (size_t)row * 1024 + tid * 4;
    f32x4 a = *(const f32x4*)(res + base);
    f32x4 b = *(const f32x4*)(p0 + base);
    f32x4 c = *(const f32x4*)(p1 + base);
    f32x4 o = a + b + c;
    *(f32x4*)(xout + base) = o;
    float ss = o[0] * o[0] + o[1] * o[1] + o[2] * o[2] + o[3] * o[3];
    #pragma unroll
    for (int off = 32; off > 0; off >>= 1) ss += __shfl_down(ss, off);
    __shared__ float red[4];
    if ((tid & 63) == 0) red[tid >> 6] = ss;
    __syncthreads();
    float sum = red[0] + red[1] + red[2] + red[3];
    float rinv = rsqrtf(sum * (1.0f / 1024.0f) + 1e-6f);
    f32x4 gv = *(const f32x4*)(g + tid * 4);
    u16x4 hv;
    #pragma unroll
    for (int i = 0; i < 4; i++) hv[i] = f2bf(o[i] * gv[i] * rinv);
    *(u16x4*)(hout + base) = hv;
}

// out = xm + a0 + a1 + a2 + a3 (all f32) — 4-way split-K reduction + residual
__global__ __launch_bounds__(256) void addred4_k(
    const float* __restrict__ xm, const float* __restrict__ a0,
    const float* __restrict__ a1, const float* __restrict__ a2,
    const float* __restrict__ a3, float* __restrict__ out)
{
    int i = (blockIdx.x * 256 + threadIdx.x) * 4;
    f32x4 v = *(const f32x4*)(xm + i);
    v = v + *(const f32x4*)(a0 + i);
    v = v + *(const f32x4*)(a1 + i);
    v = v + *(const f32x4*)(a2 + i);
    v = v + *(const f32x4*)(a3 + i);
    *(f32x4*)(out + i) = v;
}

// ---------------- GEMM (legacy 128x128, kept for Wo) ----------------
template <int MODE>
__global__ __launch_bounds__(256) void gemm_bt_k(
    const u16* __restrict__ A, const u16* __restrict__ BT,
    u16* __restrict__ outB, float* __restrict__ outF, const float* __restrict__ res,
    int M, int N, int K, int klen)
{
    __shared__ u16 As[2][128 * 64];
    __shared__ u16 Bs[2][128 * 64];
    const int tid = threadIdx.x;
    const int lane = tid & 63, w = tid >> 6;
    const int wm = w >> 1, wn = w & 1;
    const int quad = lane >> 4, l15 = lane & 15;
    const int bid = blockIdx.x + gridDim.x * blockIdx.y;
    const int bj = bid >> 3;
    const int m0 = ((bid & 7) * 4 + (bj & 3)) * 128;
    const int n0 = (bj >> 2) * 128;
    const int kbeg = blockIdx.z * klen;

    f32x4 acc[4][4] = {};

    const int srow = (w << 3) + (lane >> 3);
    const int swz = ((lane & 7) ^ (lane >> 3)) << 3;
    const u16* aA = A + (size_t)(m0 + srow) * K + kbeg + swz;
    const u16* aB = BT + (size_t)(n0 + srow) * K + kbeg + swz;
    const int wo = w * 512;
    const int rsw = (l15 & 7) << 3;

    #pragma unroll
    for (int c = 0; c < 4; c++) {
        gload_lds16(aA + (size_t)(c * 32) * K, &As[0][0] + c * 2048 + wo);
        gload_lds16(aB + (size_t)(c * 32) * K, &Bs[0][0] + c * 2048 + wo);
    }

    int cur = 0;
    for (int k0 = 0; k0 < klen; k0 += 64) {
        __syncthreads();
        if (k0 + 64 < klen) {
            #pragma unroll
            for (int c = 0; c < 4; c++) {
                gload_lds16(aA + (size_t)(c * 32) * K + k0 + 64, &As[cur ^ 1][0] + c * 2048 + wo);
                gload_lds16(aB + (size_t)(c * 32) * K + k0 + 64, &Bs[cur ^ 1][0] + c * 2048 + wo);
            }
        }
        const u16* AB = &As[cur][0];
        const u16* BB = &Bs[cur][0];
        #pragma unroll
        for (int kh = 0; kh < 2; kh++) {
            const int cb = ((kh * 4 + quad) << 3);
            bf16x8 af[4], bfr[4];
            #pragma unroll
            for (int i = 0; i < 4; i++)
                af[i] = *(const bf16x8*)(AB + (wm * 64 + i * 16 + l15) * 64 + (cb ^ rsw));
            #pragma unroll
            for (int j = 0; j < 4; j++)
                bfr[j] = *(const bf16x8*)(BB + (wn * 64 + j * 16 + l15) * 64 + (cb ^ rsw));
            #pragma unroll
            for (int i = 0; i < 4; i++)
                #pragma unroll
                for (int j = 0; j < 4; j++)
                    acc[i][j] = __builtin_amdgcn_mfma_f32_16x16x32_bf16(af[i], bfr[j], acc[i][j], 0, 0, 0);
        }
        cur ^= 1;
    }

    float* outFz = (MODE == 3) ? outF + (size_t)blockIdx.z * M * N : outF;
    #pragma unroll
    for (int i = 0; i < 4; i++) {
        const int row = m0 + wm * 64 + i * 16 + quad * 4;
        #pragma unroll
        for (int j = 0; j < 4; j++) {
            const int col = n0 + wn * 64 + j * 16 + l15;
            #pragma unroll
            for (int r = 0; r < 4; r++) {
                const size_t idx = (size_t)(row + r) * N + col;
                float v = acc[i][j][r];
                if (MODE == 0) {
                    outB[idx] = f2bf_hw(v);
                } else if (MODE == 1) {
                    outF[idx] = res[idx] + v;
                } else if (MODE == 2) {
                    float e = exp2f(v * -1.44269504088896f);
                    outB[idx] = f2bf_hw(v * __builtin_amdgcn_rcpf(1.0f + e));
                } else {
                    outFz[idx] = v;
                }
            }
        }
    }
}

// ---------------- GEMM 256x256 8-phase, row-major LDS + legacy XOR swizzle ------------
// LDS: [buf][A|B][256 rows][64 cols] (128 KiB). Staging = 4 calls/operand/tile, 8
// lanes/row -> 128B contiguous global segments (2x the old K-half staging's 64B).
// All 8 stage calls for tile t+1 issue in phases 1-2 of tile t (into the dead buf^1);
// the phase-4 vmcnt(0) then retires loads aged 2-3 phases (~free), nothing young in
// flight. Read pattern = the legacy 128² kernel's (measured 0 bank conflicts).
// MODE 0: bf16 ; MODE 2: bf16 silu ; MODE 3: f32 partial to q[blockIdx.z]
#define MMQ(FH, AS, BS) \
    { _Pragma("unroll") \
      for (int i_ = 0; i_ < 4; i_++) { \
        acc[(FH)*4+i_][0] = __builtin_amdgcn_mfma_f32_16x16x32_bf16(AS[i_], BS[0], acc[(FH)*4+i_][0], 0, 0, 0); \
        acc[(FH)*4+i_][1] = __builtin_amdgcn_mfma_f32_16x16x32_bf16(AS[i_], BS[1], acc[(FH)*4+i_][1], 0, 0, 0); \
        acc[(FH)*4+i_][2] = __builtin_amdgcn_mfma_f32_16x16x32_bf16(AS[i_], BS[2], acc[(FH)*4+i_][2], 0, 0, 0); \
        acc[(FH)*4+i_][3] = __builtin_amdgcn_mfma_f32_16x16x32_bf16(AS[i_], BS[3], acc[(FH)*4+i_][3], 0, 0, 0); \
      } }

#define SBAR   __builtin_amdgcn_s_barrier()
#define FENCE  asm volatile("" ::: "memory")

template <int MODE>
__global__ __launch_bounds__(512, 2) void gemm8p_k(
    const u16* __restrict__ A, const u16* __restrict__ BT,
    u16* __restrict__ outB, float* __restrict__ q0, float* __restrict__ q1,
    float* __restrict__ q2, float* __restrict__ q3,
    int N, int K, int klen)
{
    __shared__ u16 sm[65536];          // [buf:2][op:2][256][64]
    const int tid = threadIdx.x;
    const int lane = tid & 63, w = tid >> 6;
    const int l15 = lane & 15, quad = lane >> 4;
    const int wm = w >> 2, wn = w & 3;

    const int nwg = gridDim.x;
    const int bid = blockIdx.x;
    const int s = (bid & 7) * (nwg >> 3) + (bid >> 3);   // XCD-contiguous bands
    const int m0 = (s & 15) * 256;                       // M = 4096 fixed
    const int n0 = (s >> 4) * 256;
    const int kbeg = blockIdx.z * klen;
    const int nT = klen >> 6;

    // staging: 8 lanes/row (128B segments), XOR-8 col swizzle on the global source
    const int srow = w * 8 + (lane >> 3);                // 0..63 within a 64-row call
    const int scol = ((lane & 7) ^ (lane >> 3)) << 3;
    const u16* gA = A + (size_t)(m0 + srow) * K + kbeg + scol;
    const u16* gB = BT + (size_t)(n0 + srow) * K + kbeg + scol;
    const size_t rstep = (size_t)64 * K;                 // 64 rows per call

    const int rsw = (l15 & 7) << 3;                      // read-side unswizzle

    f32x4 acc[8][4] = {};

    auto stA = [&](int t) {                              // 4 calls, 64 rows each
        u16* d = sm + (t & 1) * 32768 + w * 512;
        const u16* g = gA + (size_t)(t * 64);
        #pragma unroll
        for (int c = 0; c < 4; c++) gload_lds16(g + c * rstep, d + c * 4096);
    };
    auto stB = [&](int t) {
        u16* d = sm + (t & 1) * 32768 + 16384 + w * 512;
        const u16* g = gB + (size_t)(t * 64);
        #pragma unroll
        for (int c = 0; c < 4; c++) gload_lds16(g + c * rstep, d + c * 4096);
    };
    auto rdA = [&](int buf, int kh, int fh, bf16x8* a) {
        const u16* p = sm + buf * 32768 + (wm * 128 + fh * 64 + l15) * 64
                       + (((kh * 4 + quad) << 3) ^ rsw);
        #pragma unroll
        for (int i = 0; i < 4; i++) a[i] = *(const bf16x8*)(p + i * 1024);
    };
    auto rdB = [&](int buf, int kh, bf16x8* b) {
        const u16* p = sm + buf * 32768 + 16384 + (wn * 64 + l15) * 64
                       + (((kh * 4 + quad) << 3) ^ rsw);
        #pragma unroll
        for (int j = 0; j < 4; j++) b[j] = *(const bf16x8*)(p + j * 1024);
    };

    // prologue: stage tile 0 fully, drain, enter loop (tile 1 staged during t=0 ph1-2)
    stA(0); stB(0);
    asm volatile("s_waitcnt vmcnt(0)" ::: "memory");
    SBAR; FENCE;

    for (int t = 0; t < nT; t++) {
        const int buf = t & 1;
        bf16x8 a[4], b[4];
        // ph1: fh0 x kh0 ; stage A(t+1)
        rdA(buf, 0, 0, a); rdB(buf, 0, b);
        if (t + 1 < nT) stA(t + 1);
        SBAR; FENCE;
        __builtin_amdgcn_s_setprio(1);
        MMQ(0, a, b)
        __builtin_amdgcn_s_setprio(0);
        SBAR; FENCE;
        // ph2: fh1 x kh0 (reuse b) ; stage B(t+1)
        rdA(buf, 0, 1, a);
        if (t + 1 < nT) stB(t + 1);
        SBAR; FENCE;
        __builtin_amdgcn_s_setprio(1);
        MMQ(1, a, b)
        __builtin_amdgcn_s_setprio(0);
        SBAR; FENCE;
        // ph3: fh0 x kh1 (no staging)
        rdA(buf, 1, 0, a); rdB(buf, 1, b);
        SBAR; FENCE;
        __builtin_amdgcn_s_setprio(1);
        MMQ(0, a, b)
        __builtin_amdgcn_s_setprio(0);
        SBAR; FENCE;
        // ph4: fh1 x kh1 ; drain tile t+1's 8 stage calls (aged 2-3 phases)
        rdA(buf, 1, 1, a);
        asm volatile("s_waitcnt vmcnt(0)" ::: "memory");
        SBAR; FENCE;
        __builtin_amdgcn_s_setprio(1);
        MMQ(1, a, b)
        __builtin_amdgcn_s_setprio(0);
        SBAR; FENCE;
    }

    float* po = nullptr;
    if (MODE == 3)
        po = (blockIdx.z == 0) ? q0 : (blockIdx.z == 1) ? q1 : (blockIdx.z == 2) ? q2 : q3;
    #pragma unroll
    for (int mf = 0; mf < 8; mf++) {
        const int row = m0 + wm * 128 + mf * 16 + quad * 4;
        #pragma unroll
        for (int nf = 0; nf < 4; nf++) {
            const int col = n0 + wn * 64 + nf * 16 + l15;
            #pragma unroll
            for (int r = 0; r < 4; r++) {
                const size_t idx = (size_t)(row + r) * N + col;
                const float v = acc[mf][nf][r];
                if (MODE == 0) {
                    outB[idx] = f2bf_hw(v);
                } else if (MODE == 2) {
                    float e = exp2f(v * -1.44269504088896f);
                    outB[idx] = f2bf_hw(v * __builtin_amdgcn_rcpf(1.0f + e));
                } else {
                    po[idx] = v;
                }
            }
        }
    }
}

// ---------------- flash attention (swapped QK^T, in-register softmax) ----------------
__global__ __launch_bounds__(256, 4) void attn_k(const u16* __restrict__ qkv,
                                                 const u16* __restrict__ vT,
                                                 u16* __restrict__ ctx)
{
    const int bh = blockIdx.x;
    const int qt = 31 - (int)blockIdx.y;
    const int b = bh >> 4, h = bh & 15;
    const int q0 = qt * 64;
    const int tid = threadIdx.x;
    const int lane = tid & 63, w = tid >> 6;
    const int quad = lane >> 4, l15 = lane & 15;

    __shared__ u16 Ks[2][4096];
    __shared__ u16 Vs[2][4096];

    const int q = q0 + 16 * w + l15;
    const u16* qrow = qkv + ((size_t)(q * 2 + b)) * 3072 + h * 64;
    const bf16x8 aq0 = *(const bf16x8*)(qrow + quad * 8);
    const bf16x8 aq1 = *(const bf16x8*)(qrow + 32 + quad * 8);

    bf16x8 ones;
    #pragma unroll
    for (int i = 0; i < 8; i++) ones[i] = (__bf16)1.0f;

    const int kr = (w << 3) + (lane >> 3);
    const int swz = ((lane & 7) ^ (lane >> 3)) << 3;
    const int ldsoff = w * 512;
    const u16* kbase0 = qkv + ((size_t)(kr * 2 + b)) * 3072 + 1024 + h * 64 + swz;
    const u16* kbase1 = kbase0 + (size_t)32 * 2 * 3072;
    const u16* vrow0 = vT + (size_t)(bh * 64 + kr) * 2048 + swz;
    const u16* vrow1 = vrow0 + (size_t)32 * 2048;

    const int sl = (l15 & 3) | ((l15 & 4) << 1) | ((l15 & 8) >> 1);
    const int rswk = (sl & 7) << 3;
    const int rswv = (l15 & 7) << 3;
    const int sq = ((quad & 1) << 1) | (quad >> 1);
    const int qloc = 16 * w + l15;

    f32x4 o[4] = {};
    f32x4 accl = {};

    gload_lds16(kbase0, &Ks[0][0] + ldsoff);
    gload_lds16(kbase1, &Ks[0][0] + 2048 + ldsoff);
    gload_lds16(vrow0, &Vs[0][0] + ldsoff);
    gload_lds16(vrow1, &Vs[0][0] + 2048 + ldsoff);

    int cur = 0;
    for (int t0 = 0; t0 <= q0; t0 += 64) {
        __syncthreads();
        if (t0 + 64 <= q0) {
            const size_t go = (size_t)(t0 + 64) * 2 * 3072;
            u16* KB = &Ks[cur ^ 1][0];
            u16* VB = &Vs[cur ^ 1][0];
            gload_lds16(kbase0 + go, KB + ldsoff);
            gload_lds16(kbase1 + go, KB + 2048 + ldsoff);
            gload_lds16(vrow0 + (t0 + 64), VB + ldsoff);
            gload_lds16(vrow1 + (t0 + 64), VB + 2048 + ldsoff);
        }
        const u16* KB = &Ks[cur][0];
        const u16* VB = &Vs[cur][0];

        f32x4 s[4];
        __builtin_amdgcn_s_setprio(1);
        #pragma unroll
        for (int tg = 0; tg < 4; tg++) {
            const u16* kb = KB + (16 * tg + sl) * 64;
            bf16x8 ak0 = *(const bf16x8*)(kb + ((quad << 3) ^ rswk));
            bf16x8 ak1 = *(const bf16x8*)(kb + (((quad + 4) << 3) ^ rswk));
            f32x4 c = {};
            c = __builtin_amdgcn_mfma_f32_16x16x32_bf16(ak0, aq0, c, 0, 0, 0);
            c = __builtin_amdgcn_mfma_f32_16x16x32_bf16(ak1, aq1, c, 0, 0, 0);
            s[tg] = c;
        }
        __builtin_amdgcn_s_setprio(0);

        if (t0 == q0) {
            #pragma unroll
            for (int tg = 0; tg < 4; tg++)
                #pragma unroll
                for (int r = 0; r < 4; r++)
                    if ((16 * tg + 4 * sq + r) > qloc) s[tg][r] = -1e30f;
        }

        unsigned dd[4][2];
        #pragma unroll
        for (int tg = 0; tg < 4; tg++) {
            float e0 = exp2f(s[tg][0]), e1 = exp2f(s[tg][1]);
            float e2 = exp2f(s[tg][2]), e3 = exp2f(s[tg][3]);
            asm("v_cvt_pk_bf16_f32 %0, %1, %2" : "=v"(dd[tg][0]) : "v"(e0), "v"(e1));
            asm("v_cvt_pk_bf16_f32 %0, %1, %2" : "=v"(dd[tg][1]) : "v"(e2), "v"(e3));
        }
        unsigned x0 = dd[0][0], y0 = dd[1][0];
        asm volatile("v_permlane32_swap_b32 %0, %1" : "+v"(x0), "+v"(y0));
        unsigned x1 = dd[0][1], y1 = dd[1][1];
        asm volatile("v_permlane32_swap_b32 %0, %1" : "+v"(x1), "+v"(y1));
        unsigned x2 = dd[2][0], y2 = dd[3][0];
        asm volatile("v_permlane32_swap_b32 %0, %1" : "+v"(x2), "+v"(y2));
        unsigned x3 = dd[2][1], y3 = dd[3][1];
        asm volatile("v_permlane32_swap_b32 %0, %1" : "+v"(x3), "+v"(y3));

        union { unsigned u[4]; bf16x8 v; } pu0, pu1;
        pu0.u[0] = x0; pu0.u[1] = x1; pu0.u[2] = y0; pu0.u[3] = y1;
        pu1.u[0] = x2; pu1.u[1] = x3; pu1.u[2] = y2; pu1.u[3] = y3;
        const bf16x8 pf0 = pu0.v, pf1 = pu1.v;

        __builtin_amdgcn_s_setprio(1);
        accl = __builtin_amdgcn_mfma_f32_16x16x32_bf16(ones, pf0, accl, 0, 0, 0);
        accl = __builtin_amdgcn_mfma_f32_16x16x32_bf16(ones, pf1, accl, 0, 0, 0);
        #pragma unroll
        for (int i = 0; i < 4; i++) {
            const u16* vb = VB + (i * 16 + l15) * 64;
            bf16x8 av0 = *(const bf16x8*)(vb + ((quad << 3) ^ rswv));
            bf16x8 av1 = *(const bf16x8*)(vb + (((quad + 4) << 3) ^ rswv));
            o[i] = __builtin_amdgcn_mfma_f32_16x16x32_bf16(av0, pf0, o[i], 0, 0, 0);
            o[i] = __builtin_amdgcn_mfma_f32_16x16x32_bf16(av1, pf1, o[i], 0, 0, 0);
        }
        __builtin_amdgcn_s_setprio(0);
        cur ^= 1;
    }

    const float linv = 1.0f / accl[0];
    #pragma unroll
    for (int i = 0; i < 4; i++) {
        u16x4 ov;
        #pragma unroll
        for (int r = 0; r < 4; r++) ov[r] = f2bf_hw(o[i][r] * linv);
        *(u16x4*)(ctx + ((size_t)(q * 2 + b)) * 1024 + h * 64 + i * 16 + quad * 4) = ov;
    }
}

// ---------------- launcher (312-us configuration) ----------------
// [0,6) bqkvT  [6,8) woT  [8,16) w1T  [16,24) w2T  [24,32) h1 (vT after QKV)
// [32,56) qkvB (xmid overlays [40,56) after attn)  [56,64) ctxB  [80,88) h2
// [88,120) partO -> actB.  W2 partials: p0 [0,16) p1 [24,40) p2 [56,72) p3 [72,88)
extern "C" void kernel_launch(void* const* d_in, const int* in_sizes, int n_in,
                              void* d_out, int out_size, void* d_ws, size_t ws_size,
                              hipStream_t stream)
{
    (void)in_sizes; (void)n_in; (void)out_size; (void)ws_size;
    const float* x  = (const float*)d_in[0];
    const float* g1 = (const float*)d_in[1];
    const float* g2 = (const float*)d_in[2];
    const float* Wq = (const float*)d_in[3];
    const float* Wk = (const float*)d_in[4];
    const float* Wv = (const float*)d_in[5];
    const float* Wo = (const float*)d_in[6];
    const float* W1 = (const float*)d_in[7];
    const float* W2 = (const float*)d_in[8];
    float* out = (float*)d_out;

    char* ws = (char*)d_ws;
    u16*   bqkvT = (u16*)(ws);
    u16*   woT   = (u16*)(ws + 6291456);
    u16*   w1T   = (u16*)(ws + 8388608);
    u16*   w2T   = (u16*)(ws + 16777216);
    u16*   h1    = (u16*)(ws + 25165824);
    u16*   qkvB  = (u16*)(ws + 33554432);
    u16*   vT    = (u16*)(ws + 25165824);         // reuses h1 (dead after QKV gemm)
    u16*   ctxB  = (u16*)(ws + 58720256);
    float* xmid  = (float*)(ws + 41943040);
    u16*   h2    = (u16*)(ws + 83886080);
    u16*   actB  = (u16*)(ws + 92274688);
    float* partO = (float*)(ws + 92274688);
    float* p0 = (float*)(ws);
    float* p1 = (float*)(ws + 25165824);
    float* p2 = (float*)(ws + 58720256);
    float* p3 = (float*)(ws + 75497472);

    // merged prep: QKV repack (768) + Wo^T (256) + W1^T (1024) + W2^T (1024) + rmsnorm (4096)
    prep_k<<<7168, 256, 0, stream>>>(Wq, Wk, Wv, Wo, W1, W2, x, g1,
                                     bqkvT, woT, w1T, w2T, h1);

    // QKV: 4096x3072x1024, 256² 8-phase (192 blocks)
    gemm8p_k<0><<<dim3(192, 1, 1), 512, 0, stream>>>(h1, bqkvT, qkvB,
                                                     nullptr, nullptr, nullptr, nullptr,
                                                     3072, 1024, 1024);
    vtrans_k<<<dim3(32, 32), 256, 0, stream>>>(qkvB, vT);
    attn_k<<<dim3(32, 32), 256, 0, stream>>>(qkvB, vT, ctxB);

    // Wo: N=1024 -> 128² split-K=2
    gemm_bt_k<3><<<dim3(8, 32, 2), 256, 0, stream>>>(ctxB, woT, nullptr, partO, nullptr,
                                                     4096, 1024, 1024, 512);
    addred_norm_k<<<4096, 256, 0, stream>>>(x, partO, partO + 4096 * 1024, g2, xmid, h2);

    // W1: 4096x4096x1024 (256 blocks, 1/CU)
    gemm8p_k<2><<<dim3(256, 1, 1), 512, 0, stream>>>(h2, w1T, actB,
                                                     nullptr, nullptr, nullptr, nullptr,
                                                     4096, 1024, 1024);
    // W2: 4096x1024x4096 split-K=4 (64x4 = 256 blocks)
    gemm8p_k<3><<<dim3(64, 1, 4), 512, 0, stream>>>(actB, w2T, nullptr,
                                                    p0, p1, p2, p3,
                                                    1024, 4096, 1024);
    addred4_k<<<4096 * 1024 / 1024, 256, 0, stream>>>(xmid, p0, p1, p2, p3, out);
}

// Round 10
// 310.404 us; speedup vs baseline: 1.0812x; 1.0161x over previous
//
#include <hip/hip_runtime.h>

typedef unsigned short u16;
typedef __bf16 bf16x8 __attribute__((ext_vector_type(8)));
typedef u16 u16x8 __attribute__((ext_vector_type(8)));
typedef u16 u16x4 __attribute__((ext_vector_type(4)));
typedef float f32x4 __attribute__((ext_vector_type(4)));

__device__ __forceinline__ u16 f2bf(float f) {
    union { float f; unsigned int u; } x; x.f = f;
    unsigned int r = x.u + 0x7FFFu + ((x.u >> 16) & 1u);
    return (u16)(r >> 16);
}

__device__ __forceinline__ u16 f2bf_hw(float f) {
    union { __bf16 b; u16 u; } x; x.b = (__bf16)f; return x.u;
}

// async global -> LDS, 16B per lane. LDS dest is wave-uniform base + lane*16.
__device__ __forceinline__ void gload_lds16(const u16* g, u16* l) {
    __builtin_amdgcn_global_load_lds(
        (const __attribute__((address_space(1))) unsigned int*)g,
        (__attribute__((address_space(3))) unsigned int*)l, 16, 0, 0);
}

// ---------------- merged prep: QKV repack + Wo/W1/W2 transpose + rmsnorm ----------------

__device__ __forceinline__ void transT_body(
    const float* __restrict__ in, u16* __restrict__ out, int R, int C,
    int bx, int by, float T[64][65], int tid)
{
    const int r0 = bx * 64, c0 = by * 64;
    const int tr = tid >> 4;
    const int tc = (tid & 15) * 4;
    #pragma unroll
    for (int k = 0; k < 4; k++) {
        f32x4 v = *(const f32x4*)(in + (size_t)(c0 + 16 * k + tr) * R + r0 + tc);
        T[16 * k + tr][tc]     = v[0];
        T[16 * k + tr][tc + 1] = v[1];
        T[16 * k + tr][tc + 2] = v[2];
        T[16 * k + tr][tc + 3] = v[3];
    }
    __syncthreads();
    #pragma unroll
    for (int k = 0; k < 4; k++) {
        const int rl = 16 * k + tr;
        u16x4 o;
        #pragma unroll
        for (int i = 0; i < 4; i++) o[i] = f2bf(T[tc + i][rl]);
        *(u16x4*)(out + (size_t)(r0 + rl) * C + c0 + tc) = o;
    }
}

__global__ __launch_bounds__(256) void prep_k(
    const float* __restrict__ Wq, const float* __restrict__ Wk,
    const float* __restrict__ Wv, const float* __restrict__ Wo,
    const float* __restrict__ W1, const float* __restrict__ W2,
    const float* __restrict__ x, const float* __restrict__ g1,
    u16* __restrict__ bqkvT, u16* __restrict__ woT,
    u16* __restrict__ w1T, u16* __restrict__ w2T, u16* __restrict__ h1)
{
    __shared__ float T[64][65];
    const int id = blockIdx.x;
    const int tid = threadIdx.x;

    if (id < 768) {
        const int bx = id & 15, y = id >> 4;
        const int d0 = bx * 64;
        const int wsel = y >> 4, h = y & 15;
        const float* W = (wsel == 0) ? Wq : (wsel == 1) ? Wk : Wv;
        const float scale = (wsel == 0) ? 0.125f * 1.44269504088896f : 1.0f;
        const int tr = tid >> 4;
        const int tc = (tid & 15) * 4;
        #pragma unroll
        for (int k = 0; k < 4; k++) {
            f32x4 v = *(const f32x4*)(W + (size_t)h * 65536 + (size_t)(d0 + 16 * k + tr) * 64 + tc);
            T[16 * k + tr][tc]     = v[0];
            T[16 * k + tr][tc + 1] = v[1];
            T[16 * k + tr][tc + 2] = v[2];
            T[16 * k + tr][tc + 3] = v[3];
        }
        __syncthreads();
        #pragma unroll
        for (int k = 0; k < 4; k++) {
            const int kk = 16 * k + tr;
            u16x4 o;
            #pragma unroll
            for (int i = 0; i < 4; i++) o[i] = f2bf(T[tc + i][kk] * scale);
            *(u16x4*)(bqkvT + (size_t)(wsel * 1024 + h * 64 + kk) * 1024 + d0 + tc) = o;
        }
    } else if (id < 1024) {
        const int id2 = id - 768;
        transT_body(Wo, woT, 1024, 1024, id2 & 15, id2 >> 4, T, tid);
    } else if (id < 2048) {
        const int id3 = id - 1024;
        transT_body(W1, w1T, 4096, 1024, id3 & 63, id3 >> 6, T, tid);
    } else if (id < 3072) {
        const int id4 = id - 2048;
        transT_body(W2, w2T, 1024, 4096, id4 & 15, id4 >> 4, T, tid);
    } else {
        const int row = id - 3072;
        const float* xr = x + (size_t)row * 1024;
        f32x4 v = *(const f32x4*)(xr + tid * 4);
        float ss = v[0] * v[0] + v[1] * v[1] + v[2] * v[2] + v[3] * v[3];
        #pragma unroll
        for (int off = 32; off > 0; off >>= 1) ss += __shfl_down(ss, off);
        float* red = &T[0][0];
        if ((tid & 63) == 0) red[tid >> 6] = ss;
        __syncthreads();
        float sum = red[0] + red[1] + red[2] + red[3];
        float rinv = rsqrtf(sum * (1.0f / 1024.0f) + 1e-6f);
        f32x4 gv = *(const f32x4*)(g1 + tid * 4);
        u16x4 o;
        #pragma unroll
        for (int i = 0; i < 4; i++) o[i] = f2bf(v[i] * gv[i] * rinv);
        *(u16x4*)(h1 + (size_t)row * 1024 + tid * 4) = o;
    }
}

// V^T: vT[(b*16+h)*64 + d][s] = qkvB[s*2+b][2048 + h*64 + d]
__global__ __launch_bounds__(256) void vtrans_k(const u16* __restrict__ qkv, u16* __restrict__ vT)
{
    __shared__ u16 T[64][72];
    const int bh = blockIdx.x, b = bh >> 4, h = bh & 15;
    const int s0 = blockIdx.y * 64;
    const int tid = threadIdx.x;
    const int r = tid >> 2, c0 = (tid & 3) * 16;
    const u16* src = qkv + ((size_t)((s0 + r) * 2 + b)) * 3072 + 2048 + h * 64 + c0;
    *(u16x8*)&T[r][c0] = *(const u16x8*)src;
    *(u16x8*)&T[r][c0 + 8] = *(const u16x8*)(src + 8);
    __syncthreads();
    u16x8 o0, o1;
    #pragma unroll
    for (int i = 0; i < 8; i++) o0[i] = T[c0 + i][r];
    #pragma unroll
    for (int i = 0; i < 8; i++) o1[i] = T[c0 + 8 + i][r];
    u16* dst = vT + (size_t)(bh * 64 + r) * 2048 + s0 + c0;
    *(u16x8*)dst = o0;
    *(u16x8*)(dst + 8) = o1;
}

// xout = res + p0 + p1 ; hout = rmsnorm(xout)*g   (block = one 1024-wide row)
__global__ __launch_bounds__(256) void addred_norm_k(
    const float* __restrict__ res, const float* __restrict__ p0,
    const float* __restrict__ p1, const float* __restrict__ g,
    float* __restrict__ xout, u16* __restrict__ hout)
{
    const int row = blockIdx.x;
    const int tid = threadIdx.x;
    const size_t base = (size_t)row * 1024 + tid * 4;
    f32x4 a = *(const f32x4*)(res + base);
    f32x4 b = *(const f32x4*)(p0 + base);
    f32x4 c = *(const f32x4*)(p1 + base);
    f32x4 o = a + b + c;
    *(f32x4*)(xout + base) = o;
    float ss = o[0] * o[0] + o[1] * o[1] + o[2] * o[2] + o[3] * o[3];
    #pragma unroll
    for (int off = 32; off > 0; off >>= 1) ss += __shfl_down(ss, off);
    __shared__ float red[4];
    if ((tid & 63) == 0) red[tid >> 6] = ss;
    __syncthreads();
    float sum = red[0] + red[1] + red[2] + red[3];
    float rinv = rsqrtf(sum * (1.0f / 1024.0f) + 1e-6f);
    f32x4 gv = *(const f32x4*)(g + tid * 4);
    u16x4 hv;
    #pragma unroll
    for (int i = 0; i < 4; i++) hv[i] = f2bf(o[i] * gv[i] * rinv);
    *(u16x4*)(hout + base) = hv;
}

// out = xm + a0 + a1 + a2 + a3 (all f32) — 4-way split-K reduction + residual
__global__ __launch_bounds__(256) void addred4_k(
    const float* __restrict__ xm, const float* __restrict__ a0,
    const float* __restrict__ a1, const float* __restrict__ a2,
    const float* __restrict__ a3, float* __restrict__ out)
{
    int i = (blockIdx.x * 256 + threadIdx.x) * 4;
    f32x4 v = *(const f32x4*)(xm + i);
    v = v + *(const f32x4*)(a0 + i);
    v = v + *(const f32x4*)(a1 + i);
    v = v + *(const f32x4*)(a2 + i);
    v = v + *(const f32x4*)(a3 + i);
    *(f32x4*)(out + i) = v;
}

// ---------------- GEMM (legacy 128x128, kept for Wo) ----------------
template <int MODE>
__global__ __launch_bounds__(256) void gemm_bt_k(
    const u16* __restrict__ A, const u16* __restrict__ BT,
    u16* __restrict__ outB, float* __restrict__ outF, const float* __restrict__ res,
    int M, int N, int K, int klen)
{
    __shared__ u16 As[2][128 * 64];
    __shared__ u16 Bs[2][128 * 64];
    const int tid = threadIdx.x;
    const int lane = tid & 63, w = tid >> 6;
    const int wm = w >> 1, wn = w & 1;
    const int quad = lane >> 4, l15 = lane & 15;
    const int bid = blockIdx.x + gridDim.x * blockIdx.y;
    const int bj = bid >> 3;
    const int m0 = ((bid & 7) * 4 + (bj & 3)) * 128;
    const int n0 = (bj >> 2) * 128;
    const int kbeg = blockIdx.z * klen;

    f32x4 acc[4][4] = {};

    const int srow = (w << 3) + (lane >> 3);
    const int swz = ((lane & 7) ^ (lane >> 3)) << 3;
    const u16* aA = A + (size_t)(m0 + srow) * K + kbeg + swz;
    const u16* aB = BT + (size_t)(n0 + srow) * K + kbeg + swz;
    const int wo = w * 512;
    const int rsw = (l15 & 7) << 3;

    #pragma unroll
    for (int c = 0; c < 4; c++) {
        gload_lds16(aA + (size_t)(c * 32) * K, &As[0][0] + c * 2048 + wo);
        gload_lds16(aB + (size_t)(c * 32) * K, &Bs[0][0] + c * 2048 + wo);
    }

    int cur = 0;
    for (int k0 = 0; k0 < klen; k0 += 64) {
        __syncthreads();
        if (k0 + 64 < klen) {
            #pragma unroll
            for (int c = 0; c < 4; c++) {
                gload_lds16(aA + (size_t)(c * 32) * K + k0 + 64, &As[cur ^ 1][0] + c * 2048 + wo);
                gload_lds16(aB + (size_t)(c * 32) * K + k0 + 64, &Bs[cur ^ 1][0] + c * 2048 + wo);
            }
        }
        const u16* AB = &As[cur][0];
        const u16* BB = &Bs[cur][0];
        #pragma unroll
        for (int kh = 0; kh < 2; kh++) {
            const int cb = ((kh * 4 + quad) << 3);
            bf16x8 af[4], bfr[4];
            #pragma unroll
            for (int i = 0; i < 4; i++)
                af[i] = *(const bf16x8*)(AB + (wm * 64 + i * 16 + l15) * 64 + (cb ^ rsw));
            #pragma unroll
            for (int j = 0; j < 4; j++)
                bfr[j] = *(const bf16x8*)(BB + (wn * 64 + j * 16 + l15) * 64 + (cb ^ rsw));
            #pragma unroll
            for (int i = 0; i < 4; i++)
                #pragma unroll
                for (int j = 0; j < 4; j++)
                    acc[i][j] = __builtin_amdgcn_mfma_f32_16x16x32_bf16(af[i], bfr[j], acc[i][j], 0, 0, 0);
        }
        cur ^= 1;
    }

    float* outFz = (MODE == 3) ? outF + (size_t)blockIdx.z * M * N : outF;
    #pragma unroll
    for (int i = 0; i < 4; i++) {
        const int row = m0 + wm * 64 + i * 16 + quad * 4;
        #pragma unroll
        for (int j = 0; j < 4; j++) {
            const int col = n0 + wn * 64 + j * 16 + l15;
            #pragma unroll
            for (int r = 0; r < 4; r++) {
                const size_t idx = (size_t)(row + r) * N + col;
                float v = acc[i][j][r];
                if (MODE == 0) {
                    outB[idx] = f2bf_hw(v);
                } else if (MODE == 1) {
                    outF[idx] = res[idx] + v;
                } else if (MODE == 2) {
                    float e = exp2f(v * -1.44269504088896f);
                    outB[idx] = f2bf_hw(v * __builtin_amdgcn_rcpf(1.0f + e));
                } else {
                    outFz[idx] = v;
                }
            }
        }
    }
}

// ---------------- GEMM 256x256, ONE barrier per K-tile (free-scheduled body) ----------
// Theory (unmeasured in R9 — infra failure, resubmitted verbatim): 8 barriers/tile at
// 1 block/CU idle the whole CU at every barrier (no other block fills the gap); all
// schedule-content variants measured identical (~27% MfmaUtil). Hazards only need the
// TILE boundary: within tile t, reads hit buf[t&1], stage writes hit buf[t&1^1]
// (disjoint). Boundary = per-wave vmcnt(0) (own staged loads aged a full tile >> HBM
// latency, ~free) + one s_barrier (publishes LDS). Compiler schedules the whole
// 64-MFMA/24-ds_read/8-stage body (m97 evidence: compiler bodies hit 900+ TF).
// MODE 0: bf16 ; MODE 2: bf16 silu ; MODE 3: f32 partial to q[blockIdx.z]
#define MMQ(FH, AS, BS) \
    { _Pragma("unroll") \
      for (int i_ = 0; i_ < 4; i_++) { \
        acc[(FH)*4+i_][0] = __builtin_amdgcn_mfma_f32_16x16x32_bf16(AS[i_], BS[0], acc[(FH)*4+i_][0], 0, 0, 0); \
        acc[(FH)*4+i_][1] = __builtin_amdgcn_mfma_f32_16x16x32_bf16(AS[i_], BS[1], acc[(FH)*4+i_][1], 0, 0, 0); \
        acc[(FH)*4+i_][2] = __builtin_amdgcn_mfma_f32_16x16x32_bf16(AS[i_], BS[2], acc[(FH)*4+i_][2], 0, 0, 0); \
        acc[(FH)*4+i_][3] = __builtin_amdgcn_mfma_f32_16x16x32_bf16(AS[i_], BS[3], acc[(FH)*4+i_][3], 0, 0, 0); \
      } }

#define SBAR   __builtin_amdgcn_s_barrier()
#define FENCE  asm volatile("" ::: "memory")

template <int MODE>
__global__ __launch_bounds__(512, 2) void gemm8p_k(
    const u16* __restrict__ A, const u16* __restrict__ BT,
    u16* __restrict__ outB, float* __restrict__ q0, float* __restrict__ q1,
    float* __restrict__ q2, float* __restrict__ q3,
    int N, int K, int klen)
{
    __shared__ u16 sm[65536];          // [buf:2][op:2][256][64]
    const int tid = threadIdx.x;
    const int lane = tid & 63, w = tid >> 6;
    const int l15 = lane & 15, quad = lane >> 4;
    const int wm = w >> 2, wn = w & 3;

    const int nwg = gridDim.x;
    const int bid = blockIdx.x;
    const int s = (bid & 7) * (nwg >> 3) + (bid >> 3);   // XCD-contiguous bands
    const int m0 = (s & 15) * 256;                       // M = 4096 fixed
    const int n0 = (s >> 4) * 256;
    const int kbeg = blockIdx.z * klen;
    const int nT = klen >> 6;

    // staging: 8 lanes/row (128B segments), XOR-8 col swizzle on the global source
    const int srow = w * 8 + (lane >> 3);                // 0..63 within a 64-row call
    const int scol = ((lane & 7) ^ (lane >> 3)) << 3;
    const u16* gA = A + (size_t)(m0 + srow) * K + kbeg + scol;
    const u16* gB = BT + (size_t)(n0 + srow) * K + kbeg + scol;
    const size_t rstep = (size_t)64 * K;                 // 64 rows per call

    const int rsw = (l15 & 7) << 3;                      // read-side unswizzle

    f32x4 acc[8][4] = {};

    auto stA = [&](int t) {                              // 4 calls, 64 rows each
        u16* d = sm + (t & 1) * 32768 + w * 512;
        const u16* g = gA + (size_t)(t * 64);
        #pragma unroll
        for (int c = 0; c < 4; c++) gload_lds16(g + c * rstep, d + c * 4096);
    };
    auto stB = [&](int t) {
        u16* d = sm + (t & 1) * 32768 + 16384 + w * 512;
        const u16* g = gB + (size_t)(t * 64);
        #pragma unroll
        for (int c = 0; c < 4; c++) gload_lds16(g + c * rstep, d + c * 4096);
    };
    auto rdA = [&](int buf, int kh, int fh, bf16x8* a) {
        const u16* p = sm + buf * 32768 + (wm * 128 + fh * 64 + l15) * 64
                       + (((kh * 4 + quad) << 3) ^ rsw);
        #pragma unroll
        for (int i = 0; i < 4; i++) a[i] = *(const bf16x8*)(p + i * 1024);
    };
    auto rdB = [&](int buf, int kh, bf16x8* b) {
        const u16* p = sm + buf * 32768 + 16384 + (wn * 64 + l15) * 64
                       + (((kh * 4 + quad) << 3) ^ rsw);
        #pragma unroll
        for (int j = 0; j < 4; j++) b[j] = *(const bf16x8*)(p + j * 1024);
    };

    // prologue: stage tile 0, drain, enter loop
    stA(0); stB(0);
    asm volatile("s_waitcnt vmcnt(0)" ::: "memory");
    SBAR; FENCE;

    for (int t = 0; t < nT; t++) {
        const int buf = t & 1;
        // issue next tile's staging up front (targets buf^1 — disjoint from all reads)
        if (t + 1 < nT) { stA(t + 1); stB(t + 1); }
        bf16x8 a[4], b[4];
        // free-scheduled tile body: no intra-tile barriers, no setprio, no fences
        rdA(buf, 0, 0, a); rdB(buf, 0, b);
        MMQ(0, a, b)
        rdA(buf, 0, 1, a);
        MMQ(1, a, b)
        rdA(buf, 1, 0, a); rdB(buf, 1, b);
        MMQ(0, a, b)
        rdA(buf, 1, 1, a);
        MMQ(1, a, b)
        // tile boundary: own staged loads landed + block-wide publish
        asm volatile("s_waitcnt vmcnt(0)" ::: "memory");
        SBAR; FENCE;
    }

    float* po = nullptr;
    if (MODE == 3)
        po = (blockIdx.z == 0) ? q0 : (blockIdx.z == 1) ? q1 : (blockIdx.z == 2) ? q2 : q3;
    #pragma unroll
    for (int mf = 0; mf < 8; mf++) {
        const int row = m0 + wm * 128 + mf * 16 + quad * 4;
        #pragma unroll
        for (int nf = 0; nf < 4; nf++) {
            const int col = n0 + wn * 64 + nf * 16 + l15;
            #pragma unroll
            for (int r = 0; r < 4; r++) {
                const size_t idx = (size_t)(row + r) * N + col;
                const float v = acc[mf][nf][r];
                if (MODE == 0) {
                    outB[idx] = f2bf_hw(v);
                } else if (MODE == 2) {
                    float e = exp2f(v * -1.44269504088896f);
                    outB[idx] = f2bf_hw(v * __builtin_amdgcn_rcpf(1.0f + e));
                } else {
                    po[idx] = v;
                }
            }
        }
    }
}

// ---------------- flash attention (swapped QK^T, in-register softmax) ----------------
__global__ __launch_bounds__(256, 4) void attn_k(const u16* __restrict__ qkv,
                                                 const u16* __restrict__ vT,
                                                 u16* __restrict__ ctx)
{
    const int bh = blockIdx.x;
    const int qt = 31 - (int)blockIdx.y;
    const int b = bh >> 4, h = bh & 15;
    const int q0 = qt * 64;
    const int tid = threadIdx.x;
    const int lane = tid & 63, w = tid >> 6;
    const int quad = lane >> 4, l15 = lane & 15;

    __shared__ u16 Ks[2][4096];
    __shared__ u16 Vs[2][4096];

    const int q = q0 + 16 * w + l15;
    const u16* qrow = qkv + ((size_t)(q * 2 + b)) * 3072 + h * 64;
    const bf16x8 aq0 = *(const bf16x8*)(qrow + quad * 8);
    const bf16x8 aq1 = *(const bf16x8*)(qrow + 32 + quad * 8);

    bf16x8 ones;
    #pragma unroll
    for (int i = 0; i < 8; i++) ones[i] = (__bf16)1.0f;

    const int kr = (w << 3) + (lane >> 3);
    const int swz = ((lane & 7) ^ (lane >> 3)) << 3;
    const int ldsoff = w * 512;
    const u16* kbase0 = qkv + ((size_t)(kr * 2 + b)) * 3072 + 1024 + h * 64 + swz;
    const u16* kbase1 = kbase0 + (size_t)32 * 2 * 3072;
    const u16* vrow0 = vT + (size_t)(bh * 64 + kr) * 2048 + swz;
    const u16* vrow1 = vrow0 + (size_t)32 * 2048;

    const int sl = (l15 & 3) | ((l15 & 4) << 1) | ((l15 & 8) >> 1);
    const int rswk = (sl & 7) << 3;
    const int rswv = (l15 & 7) << 3;
    const int sq = ((quad & 1) << 1) | (quad >> 1);
    const int qloc = 16 * w + l15;

    f32x4 o[4] = {};
    f32x4 accl = {};

    gload_lds16(kbase0, &Ks[0][0] + ldsoff);
    gload_lds16(kbase1, &Ks[0][0] + 2048 + ldsoff);
    gload_lds16(vrow0, &Vs[0][0] + ldsoff);
    gload_lds16(vrow1, &Vs[0][0] + 2048 + ldsoff);

    int cur = 0;
    for (int t0 = 0; t0 <= q0; t0 += 64) {
        __syncthreads();
        if (t0 + 64 <= q0) {
            const size_t go = (size_t)(t0 + 64) * 2 * 3072;
            u16* KB = &Ks[cur ^ 1][0];
            u16* VB = &Vs[cur ^ 1][0];
            gload_lds16(kbase0 + go, KB + ldsoff);
            gload_lds16(kbase1 + go, KB + 2048 + ldsoff);
            gload_lds16(vrow0 + (t0 + 64), VB + ldsoff);
            gload_lds16(vrow1 + (t0 + 64), VB + 2048 + ldsoff);
        }
        const u16* KB = &Ks[cur][0];
        const u16* VB = &Vs[cur][0];

        f32x4 s[4];
        __builtin_amdgcn_s_setprio(1);
        #pragma unroll
        for (int tg = 0; tg < 4; tg++) {
            const u16* kb = KB + (16 * tg + sl) * 64;
            bf16x8 ak0 = *(const bf16x8*)(kb + ((quad << 3) ^ rswk));
            bf16x8 ak1 = *(const bf16x8*)(kb + (((quad + 4) << 3) ^ rswk));
            f32x4 c = {};
            c = __builtin_amdgcn_mfma_f32_16x16x32_bf16(ak0, aq0, c, 0, 0, 0);
            c = __builtin_amdgcn_mfma_f32_16x16x32_bf16(ak1, aq1, c, 0, 0, 0);
            s[tg] = c;
        }
        __builtin_amdgcn_s_setprio(0);

        if (t0 == q0) {
            #pragma unroll
            for (int tg = 0; tg < 4; tg++)
                #pragma unroll
                for (int r = 0; r < 4; r++)
                    if ((16 * tg + 4 * sq + r) > qloc) s[tg][r] = -1e30f;
        }

        unsigned dd[4][2];
        #pragma unroll
        for (int tg = 0; tg < 4; tg++) {
            float e0 = exp2f(s[tg][0]), e1 = exp2f(s[tg][1]);
            float e2 = exp2f(s[tg][2]), e3 = exp2f(s[tg][3]);
            asm("v_cvt_pk_bf16_f32 %0, %1, %2" : "=v"(dd[tg][0]) : "v"(e0), "v"(e1));
            asm("v_cvt_pk_bf16_f32 %0, %1, %2" : "=v"(dd[tg][1]) : "v"(e2), "v"(e3));
        }
        unsigned x0 = dd[0][0], y0 = dd[1][0];
        asm volatile("v_permlane32_swap_b32 %0, %1" : "+v"(x0), "+v"(y0));
        unsigned x1 = dd[0][1], y1 = dd[1][1];
        asm volatile("v_permlane32_swap_b32 %0, %1" : "+v"(x1), "+v"(y1));
        unsigned x2 = dd[2][0], y2 = dd[3][0];
        asm volatile("v_permlane32_swap_b32 %0, %1" : "+v"(x2), "+v"(y2));
        unsigned x3 = dd[2][1], y3 = dd[3][1];
        asm volatile("v_permlane32_swap_b32 %0, %1" : "+v"(x3), "+v"(y3));

        union { unsigned u[4]; bf16x8 v; } pu0, pu1;
        pu0.u[0] = x0; pu0.u[1] = x1; pu0.u[2] = y0; pu0.u[3] = y1;
        pu1.u[0] = x2; pu1.u[1] = x3; pu1.u[2] = y2; pu1.u[3] = y3;
        const bf16x8 pf0 = pu0.v, pf1 = pu1.v;

        __builtin_amdgcn_s_setprio(1);
        accl = __builtin_amdgcn_mfma_f32_16x16x32_bf16(ones, pf0, accl, 0, 0, 0);
        accl = __builtin_amdgcn_mfma_f32_16x16x32_bf16(ones, pf1, accl, 0, 0, 0);
        #pragma unroll
        for (int i = 0; i < 4; i++) {
            const u16* vb = VB + (i * 16 + l15) * 64;
            bf16x8 av0 = *(const bf16x8*)(vb + ((quad << 3) ^ rswv));
            bf16x8 av1 = *(const bf16x8*)(vb + (((quad + 4) << 3) ^ rswv));
            o[i] = __builtin_amdgcn_mfma_f32_16x16x32_bf16(av0, pf0, o[i], 0, 0, 0);
            o[i] = __builtin_amdgcn_mfma_f32_16x16x32_bf16(av1, pf1, o[i], 0, 0, 0);
        }
        __builtin_amdgcn_s_setprio(0);
        cur ^= 1;
    }

    const float linv = 1.0f / accl[0];
    #pragma unroll
    for (int i = 0; i < 4; i++) {
        u16x4 ov;
        #pragma unroll
        for (int r = 0; r < 4; r++) ov[r] = f2bf_hw(o[i][r] * linv);
        *(u16x4*)(ctx + ((size_t)(q * 2 + b)) * 1024 + h * 64 + i * 16 + quad * 4) = ov;
    }
}

// ---------------- launcher (R5/R8 configuration) ----------------
// [0,6) bqkvT  [6,8) woT  [8,16) w1T  [16,24) w2T  [24,32) h1 (vT after QKV)
// [32,56) qkvB (xmid overlays [40,56) after attn)  [56,64) ctxB  [80,88) h2
// [88,120) partO -> actB.  W2 partials: p0 [0,16) p1 [24,40) p2 [56,72) p3 [72,88)
extern "C" void kernel_launch(void* const* d_in, const int* in_sizes, int n_in,
                              void* d_out, int out_size, void* d_ws, size_t ws_size,
                              hipStream_t stream)
{
    (void)in_sizes; (void)n_in; (void)out_size; (void)ws_size;
    const float* x  = (const float*)d_in[0];
    const float* g1 = (const float*)d_in[1];
    const float* g2 = (const float*)d_in[2];
    const float* Wq = (const float*)d_in[3];
    const float* Wk = (const float*)d_in[4];
    const float* Wv = (const float*)d_in[5];
    const float* Wo = (const float*)d_in[6];
    const float* W1 = (const float*)d_in[7];
    const float* W2 = (const float*)d_in[8];
    float* out = (float*)d_out;

    char* ws = (char*)d_ws;
    u16*   bqkvT = (u16*)(ws);
    u16*   woT   = (u16*)(ws + 6291456);
    u16*   w1T   = (u16*)(ws + 8388608);
    u16*   w2T   = (u16*)(ws + 16777216);
    u16*   h1    = (u16*)(ws + 25165824);
    u16*   qkvB  = (u16*)(ws + 33554432);
    u16*   vT    = (u16*)(ws + 25165824);         // reuses h1 (dead after QKV gemm)
    u16*   ctxB  = (u16*)(ws + 58720256);
    float* xmid  = (float*)(ws + 41943040);
    u16*   h2    = (u16*)(ws + 83886080);
    u16*   actB  = (u16*)(ws + 92274688);
    float* partO = (float*)(ws + 92274688);
    float* p0 = (float*)(ws);
    float* p1 = (float*)(ws + 25165824);
    float* p2 = (float*)(ws + 58720256);
    float* p3 = (float*)(ws + 75497472);

    // merged prep: QKV repack (768) + Wo^T (256) + W1^T (1024) + W2^T (1024) + rmsnorm (4096)
    prep_k<<<7168, 256, 0, stream>>>(Wq, Wk, Wv, Wo, W1, W2, x, g1,
                                     bqkvT, woT, w1T, w2T, h1);

    // QKV: 4096x3072x1024 (192 blocks)
    gemm8p_k<0><<<dim3(192, 1, 1), 512, 0, stream>>>(h1, bqkvT, qkvB,
                                                     nullptr, nullptr, nullptr, nullptr,
                                                     3072, 1024, 1024);
    vtrans_k<<<dim3(32, 32), 256, 0, stream>>>(qkvB, vT);
    attn_k<<<dim3(32, 32), 256, 0, stream>>>(qkvB, vT, ctxB);

    // Wo: N=1024 -> 128² split-K=2
    gemm_bt_k<3><<<dim3(8, 32, 2), 256, 0, stream>>>(ctxB, woT, nullptr, partO, nullptr,
                                                     4096, 1024, 1024, 512);
    addred_norm_k<<<4096, 256, 0, stream>>>(x, partO, partO + 4096 * 1024, g2, xmid, h2);

    // W1: 4096x4096x1024 (256 blocks, 1/CU)
    gemm8p_k<2><<<dim3(256, 1, 1), 512, 0, stream>>>(h2, w1T, actB,
                                                     nullptr, nullptr, nullptr, nullptr,
                                                     4096, 1024, 1024);
    // W2: 4096x1024x4096 split-K=4 (64x4 = 256 blocks)
    gemm8p_k<3><<<dim3(64, 1, 4), 512, 0, stream>>>(actB, w2T, nullptr,
                                                    p0, p1, p2, p3,
                                                    1024, 4096, 1024);
    addred4_k<<<4096 * 1024 / 1024, 256, 0, stream>>>(xmid, p0, p1, p2, p3, out);
}